// Round 2
// baseline (2320.277 us; speedup 1.0000x reference)
//
#include <hip/hip_runtime.h>
#include <hip/hip_bf16.h>

#define N_NODES 50000
#define N_GRAPHS 500
#define N_EDGES 800000

static inline int cdiv(int a, int b) { return (a + b - 1) / b; }

// ---------------- CSR build ----------------

__global__ void count_kernel(const int* __restrict__ row, int* __restrict__ cnt, int e) {
    int t = blockIdx.x * blockDim.x + threadIdx.x;
    if (t < e) atomicAdd(&cnt[row[t]], 1);
}

// Single-block exclusive scan of cnt[0..n) -> rp[0..n], 8 elems/thread chunks.
__global__ void scan_kernel(const int* __restrict__ cnt, int* __restrict__ rp, int n) {
    const int T = 1024, VPT = 8, CHUNK = T * VPT;
    __shared__ int buf[2][1024];
    __shared__ int carry_s;
    int t = threadIdx.x;
    if (t == 0) carry_s = 0;
    __syncthreads();
    for (int base = 0; base < n; base += CHUNK) {
        int v[VPT];
        int lsum = 0;
#pragma unroll
        for (int i = 0; i < VPT; ++i) {
            int idx = base + t * VPT + i;
            v[i] = (idx < n) ? cnt[idx] : 0;
            lsum += v[i];
        }
        buf[0][t] = lsum;
        __syncthreads();
        int src = 0;
#pragma unroll
        for (int off = 1; off < 1024; off <<= 1) {
            int val = buf[src][t];
            if (t >= off) val += buf[src][t - off];
            buf[src ^ 1][t] = val;
            src ^= 1;
            __syncthreads();
        }
        int inc = buf[src][t];  // inclusive scan of per-thread sums
        int carry = carry_s;
        __syncthreads();
        int run = carry + inc - lsum;  // exclusive prefix at this thread's first elem
#pragma unroll
        for (int i = 0; i < VPT; ++i) {
            int idx = base + t * VPT + i;
            if (idx < n) rp[idx] = run;
            run += v[i];
        }
        if (t == T - 1) carry_s = carry + inc;
        __syncthreads();
    }
    if (t == 0) rp[n] = carry_s;
}

__global__ void dinv_cursor_kernel(const int* __restrict__ cnt, const int* __restrict__ rp,
                                   float* __restrict__ dinv, int* __restrict__ cursor, int n) {
    int t = blockIdx.x * blockDim.x + threadIdx.x;
    if (t < n) {
        int c = cnt[t];
        dinv[t] = (c > 0) ? rsqrtf((float)c) : 0.0f;
        cursor[t] = rp[t];
    }
}

__global__ void fill_kernel(const int* __restrict__ row, const int* __restrict__ col,
                            const float* __restrict__ dinv, int* __restrict__ cursor,
                            int* __restrict__ ci, float* __restrict__ cw, int e) {
    int t = blockIdx.x * blockDim.x + threadIdx.x;
    if (t < e) {
        int r = row[t], c = col[t];
        int slot = atomicAdd(&cursor[r], 1);
        ci[slot] = c;
        cw[slot] = -dinv[r] * dinv[c];
    }
}

// ---------------- sparse matvec (per Chebyshev step) ----------------

template <int F>
__global__ void spmm_plain(const int* __restrict__ rp, const int* __restrict__ ci,
                           const float* __restrict__ cw, const float* __restrict__ h,
                           float* __restrict__ out) {
    int t = blockIdx.x * blockDim.x + threadIdx.x;
    if (t >= N_NODES * F) return;
    int node = t / F;
    int f = t - node * F;
    float s = 0.0f;
    int e1 = rp[node + 1];
    for (int j = rp[node]; j < e1; ++j) s += cw[j] * h[ci[j] * F + f];
    out[t] = s;
}

template <int F>
__global__ void spmm_recur(const int* __restrict__ rp, const int* __restrict__ ci,
                           const float* __restrict__ cw, const float* __restrict__ h,
                           const float* __restrict__ tx0, float* __restrict__ out) {
    int t = blockIdx.x * blockDim.x + threadIdx.x;
    if (t >= N_NODES * F) return;
    int node = t / F;
    int f = t - node * F;
    float s = 0.0f;
    int e1 = rp[node + 1];
    for (int j = rp[node]; j < e1; ++j) s += cw[j] * h[ci[j] * F + f];
    out[t] = 2.0f * s - tx0[t];
}

// ---------------- dense matmul: out[N,FOUT] (+)= A[N,FIN] @ W[FIN,FOUT] ----------------

template <int FIN, int FOUT, bool ACC>
__global__ __launch_bounds__(256) void matmul_kernel(const float* __restrict__ A,
                                                     const float* __restrict__ W,
                                                     float* __restrict__ out) {
    constexpr int TN = FOUT / 16;  // 2,4,8
    constexpr int KC = 16;
    __shared__ float lds_a[KC][64 + 4];   // [k][node], +4 pad keeps 16B align per row
    __shared__ float lds_w[KC][FOUT];
    int tid = threadIdx.x;
    int tr = tid >> 4;   // node group 0..15
    int tc = tid & 15;   // fo group 0..15
    int node0 = blockIdx.x * 64;

    float acc[4][TN];
#pragma unroll
    for (int i = 0; i < 4; ++i)
#pragma unroll
        for (int j = 0; j < TN; ++j) acc[i][j] = 0.0f;

    for (int k0 = 0; k0 < FIN; k0 += KC) {
        // stage A tile transposed: 64 nodes x KC
#pragma unroll
        for (int i = 0; i < 4; ++i) {
            int flat = tid + i * 256;  // 0..1023
            int nn = flat >> 4, kk = flat & 15;
            int gn = node0 + nn, gk = k0 + kk;
            float v = 0.0f;
            if (gn < N_NODES && gk < FIN) v = A[(size_t)gn * FIN + gk];
            lds_a[kk][nn] = v;
        }
        // stage W chunk
        constexpr int WTOT = KC * FOUT;
#pragma unroll
        for (int i = 0; i < WTOT / 256; ++i) {
            int flat = tid + i * 256;
            int kk = flat / FOUT, ff = flat % FOUT;
            int gk = k0 + kk;
            lds_w[kk][ff] = (gk < FIN) ? W[(size_t)gk * FOUT + ff] : 0.0f;
        }
        __syncthreads();
#pragma unroll
        for (int k = 0; k < KC; ++k) {
            float4 a = *(const float4*)&lds_a[k][tr * 4];
            float av[4] = {a.x, a.y, a.z, a.w};
            float w[TN];
#pragma unroll
            for (int j = 0; j < TN; ++j) w[j] = lds_w[k][tc * TN + j];
#pragma unroll
            for (int i = 0; i < 4; ++i)
#pragma unroll
                for (int j = 0; j < TN; ++j) acc[i][j] += av[i] * w[j];
        }
        __syncthreads();
    }
#pragma unroll
    for (int i = 0; i < 4; ++i) {
        int gn = node0 + tr * 4 + i;
        if (gn < N_NODES) {
#pragma unroll
            for (int j = 0; j < TN; ++j) {
                size_t idx = (size_t)gn * FOUT + tc * TN + j;
                if (ACC)
                    out[idx] += acc[i][j];
                else
                    out[idx] = acc[i][j];
            }
        }
    }
}

template <int F>
__global__ void relu_bias_kernel(float* __restrict__ h, const float* __restrict__ b) {
    int t = blockIdx.x * blockDim.x + threadIdx.x;
    if (t < N_NODES * F) {
        int f = t % F;
        h[t] = fmaxf(h[t] + b[f], 0.0f);
    }
}

// ---------------- pooling + linear + log_softmax ----------------

__global__ void pool_head_kernel(const float* __restrict__ h, const int* __restrict__ batch,
                                 const float* __restrict__ lw, const float* __restrict__ lb,
                                 float* __restrict__ out) {
    int g = blockIdx.x;
    int f = threadIdx.x;  // 128 threads, one per feature
    // lower_bound(batch, g) and lower_bound(batch, g+1)
    int s = 0, e = N_NODES;
    {
        int lo = 0, hi = N_NODES;
        while (lo < hi) { int mid = (lo + hi) >> 1; if (batch[mid] < g) lo = mid + 1; else hi = mid; }
        s = lo;
        lo = s; hi = N_NODES;
        while (lo < hi) { int mid = (lo + hi) >> 1; if (batch[mid] < g + 1) lo = mid + 1; else hi = mid; }
        e = lo;
    }
    float sum = 0.0f;
    for (int i = s; i < e; ++i) sum += h[(size_t)i * 128 + f];
    float cnt = (float)(e - s);
    float pooled = sum / fmaxf(cnt, 1.0f);

    __shared__ float l0[128], l1[128];
    l0[f] = pooled * lw[f * 2 + 0];
    l1[f] = pooled * lw[f * 2 + 1];
    __syncthreads();
    for (int sdt = 64; sdt > 0; sdt >>= 1) {
        if (f < sdt) { l0[f] += l0[f + sdt]; l1[f] += l1[f + sdt]; }
        __syncthreads();
    }
    if (f == 0) {
        float a = l0[0] + lb[0], b = l1[0] + lb[1];
        float m = fmaxf(a, b);
        float lse = m + logf(expf(a - m) + expf(b - m));
        out[g * 2 + 0] = a - lse;
        out[g * 2 + 1] = b - lse;
    }
}

// ---------------- per-layer driver ----------------

template <int FIN, int FOUT>
static void run_layer(const float* h, float* out, float* S0, float* S1, float* S2,
                      const float* W, const float* b, const int* rp, const int* ci,
                      const float* cw, hipStream_t s) {
    dim3 blk(256);
    int mm_grid = cdiv(N_NODES, 64);
    int sp_grid = cdiv(N_NODES * FIN, 256);
    int rb_grid = cdiv(N_NODES * FOUT, 256);
    const float* W0 = W;
    const float* W1 = W + (size_t)1 * FIN * FOUT;
    const float* W2 = W + (size_t)2 * FIN * FOUT;
    const float* W3 = W + (size_t)3 * FIN * FOUT;
    const float* W4 = W + (size_t)4 * FIN * FOUT;

    // T0 = h
    matmul_kernel<FIN, FOUT, false><<<mm_grid, blk, 0, s>>>(h, W0, out);
    // T1 = Lx(T0)
    spmm_plain<FIN><<<sp_grid, blk, 0, s>>>(rp, ci, cw, h, S0);
    matmul_kernel<FIN, FOUT, true><<<mm_grid, blk, 0, s>>>(S0, W1, out);
    // T2 = 2 Lx(T1) - T0
    spmm_recur<FIN><<<sp_grid, blk, 0, s>>>(rp, ci, cw, S0, h, S1);
    matmul_kernel<FIN, FOUT, true><<<mm_grid, blk, 0, s>>>(S1, W2, out);
    // T3 = 2 Lx(T2) - T1
    spmm_recur<FIN><<<sp_grid, blk, 0, s>>>(rp, ci, cw, S1, S0, S2);
    matmul_kernel<FIN, FOUT, true><<<mm_grid, blk, 0, s>>>(S2, W3, out);
    // T4 = 2 Lx(T3) - T2  (reuse S0, old T1 dead)
    spmm_recur<FIN><<<sp_grid, blk, 0, s>>>(rp, ci, cw, S2, S1, S0);
    matmul_kernel<FIN, FOUT, true><<<mm_grid, blk, 0, s>>>(S0, W4, out);
    // h_next = relu(out + b), in place
    relu_bias_kernel<FOUT><<<rb_grid, blk, 0, s>>>(out, b);
}

extern "C" void kernel_launch(void* const* d_in, const int* in_sizes, int n_in,
                              void* d_out, int out_size, void* d_ws, size_t ws_size,
                              hipStream_t stream) {
    const float* x = (const float*)d_in[0];
    const int* ei = (const int*)d_in[1];
    const int* batch = (const int*)d_in[2];
    const float* W1 = (const float*)d_in[3];
    const float* b1 = (const float*)d_in[4];
    const float* W2 = (const float*)d_in[5];
    const float* b2 = (const float*)d_in[6];
    const float* W3 = (const float*)d_in[7];
    const float* b3 = (const float*)d_in[8];
    const float* W4 = (const float*)d_in[9];
    const float* b4 = (const float*)d_in[10];
    const float* W5 = (const float*)d_in[11];
    const float* b5 = (const float*)d_in[12];
    const float* lin_w = (const float*)d_in[13];
    const float* lin_b = (const float*)d_in[14];
    const int* row = ei;
    const int* col = ei + N_EDGES;
    float* out = (float*)d_out;

    char* p = (char*)d_ws;
    auto alloc = [&](size_t bytes) {
        char* r = p;
        p += (bytes + 255) & ~(size_t)255;
        return r;
    };
    int* cnt = (int*)alloc((size_t)N_NODES * 4);
    int* rp = (int*)alloc((size_t)(N_NODES + 1) * 4);
    int* cursor = (int*)alloc((size_t)N_NODES * 4);
    float* dinv = (float*)alloc((size_t)N_NODES * 4);
    int* ci = (int*)alloc((size_t)N_EDGES * 4);
    float* cw = (float*)alloc((size_t)N_EDGES * 4);
    float* S0 = (float*)alloc((size_t)N_NODES * 116 * 4);
    float* S1 = (float*)alloc((size_t)N_NODES * 116 * 4);
    float* S2 = (float*)alloc((size_t)N_NODES * 116 * 4);
    float* O1 = (float*)alloc((size_t)N_NODES * 128 * 4);
    float* O2 = (float*)alloc((size_t)N_NODES * 128 * 4);

    hipMemsetAsync(cnt, 0, (size_t)N_NODES * 4, stream);
    count_kernel<<<cdiv(N_EDGES, 256), 256, 0, stream>>>(row, cnt, N_EDGES);
    scan_kernel<<<1, 1024, 0, stream>>>(cnt, rp, N_NODES);
    dinv_cursor_kernel<<<cdiv(N_NODES, 256), 256, 0, stream>>>(cnt, rp, dinv, cursor, N_NODES);
    fill_kernel<<<cdiv(N_EDGES, 256), 256, 0, stream>>>(row, col, dinv, cursor, ci, cw, N_EDGES);

    run_layer<116, 32>(x, O1, S0, S1, S2, W1, b1, rp, ci, cw, stream);
    run_layer<32, 32>(O1, O2, S0, S1, S2, W2, b2, rp, ci, cw, stream);
    run_layer<32, 64>(O2, O1, S0, S1, S2, W3, b3, rp, ci, cw, stream);
    run_layer<64, 64>(O1, O2, S0, S1, S2, W4, b4, rp, ci, cw, stream);
    run_layer<64, 128>(O2, O1, S0, S1, S2, W5, b5, rp, ci, cw, stream);

    pool_head_kernel<<<N_GRAPHS, 128, 0, stream>>>(O1, batch, lin_w, lin_b, out);
}

// Round 4
// 1066.035 us; speedup vs baseline: 2.1765x; 2.1765x over previous
//
#include <hip/hip_runtime.h>

#define N_NODES 50000
#define N_GRAPHS 500
#define N_EDGES 800000

static inline int cdiv(int a, int b) { return (a + b - 1) / b; }

// ---------------- CSR build ----------------

__global__ void count_kernel(const int* __restrict__ row, int* __restrict__ cnt, int e) {
    int t = blockIdx.x * blockDim.x + threadIdx.x;
    if (t < e) atomicAdd(&cnt[row[t]], 1);
}

// Single-block exclusive scan of cnt[0..n) -> rp[0..n].
__global__ void scan_kernel(const int* __restrict__ cnt, int* __restrict__ rp, int n) {
    const int T = 1024, VPT = 8, CHUNK = T * VPT;
    __shared__ int buf[2][1024];
    __shared__ int carry_s;
    int t = threadIdx.x;
    if (t == 0) carry_s = 0;
    __syncthreads();
    for (int base = 0; base < n; base += CHUNK) {
        int v[VPT];
        int lsum = 0;
#pragma unroll
        for (int i = 0; i < VPT; ++i) {
            int idx = base + t * VPT + i;
            v[i] = (idx < n) ? cnt[idx] : 0;
            lsum += v[i];
        }
        buf[0][t] = lsum;
        __syncthreads();
        int src = 0;
#pragma unroll
        for (int off = 1; off < 1024; off <<= 1) {
            int val = buf[src][t];
            if (t >= off) val += buf[src][t - off];
            buf[src ^ 1][t] = val;
            src ^= 1;
            __syncthreads();
        }
        int inc = buf[src][t];
        int carry = carry_s;
        __syncthreads();
        int run = carry + inc - lsum;
#pragma unroll
        for (int i = 0; i < VPT; ++i) {
            int idx = base + t * VPT + i;
            if (idx < n) rp[idx] = run;
            run += v[i];
        }
        if (t == T - 1) carry_s = carry + inc;
        __syncthreads();
    }
    if (t == 0) rp[n] = carry_s;
}

__global__ void dinv_cursor_kernel(const int* __restrict__ cnt, const int* __restrict__ rp,
                                   float* __restrict__ dinv, int* __restrict__ cursor, int n) {
    int t = blockIdx.x * blockDim.x + threadIdx.x;
    if (t < n) {
        int c = cnt[t];
        dinv[t] = (c > 0) ? rsqrtf((float)c) : 0.0f;
        cursor[t] = rp[t];
    }
}

__global__ void fill_kernel(const int* __restrict__ row, const int* __restrict__ col,
                            const float* __restrict__ dinv, int* __restrict__ cursor,
                            int* __restrict__ ci, float* __restrict__ cw, int e) {
    int t = blockIdx.x * blockDim.x + threadIdx.x;
    if (t < e) {
        int r = row[t], c = col[t];
        int slot = atomicAdd(&cursor[r], 1);
        ci[slot] = c;
        cw[slot] = -dinv[r] * dinv[c];
    }
}

// Repack W1 [5][116][32] -> Wc [116][160], Wc[fin][k*32+fo] = W1[k][fin][fo]
__global__ void repack_w1(const float* __restrict__ W, float* __restrict__ Wc) {
    int t = blockIdx.x * blockDim.x + threadIdx.x;
    if (t < 5 * 116 * 32) {
        int k = t / (116 * 32);
        int r = t % (116 * 32);
        int fin = r / 32, fo = r % 32;
        Wc[fin * 160 + k * 32 + fo] = W[t];
    }
}

// ---------------- fused SpMM: out = alpha*L(src) + cA*A + cB*B (+bias,relu) ----------------
// L(src)[n,f] = sum_j cw[j] * src[ci[j]*ld_s + f], j over CSR row n.
// All column-slice pointers are pre-offset; ld_* are row strides in floats.

template <int F, bool HAS_A, bool HAS_B, bool RELU>
__global__ __launch_bounds__(256) void spmm_fused(
    const int* __restrict__ rp, const int* __restrict__ ci, const float* __restrict__ cw,
    const float* __restrict__ src, int ld_s, float alpha,
    const float* __restrict__ A, int ldA, float cA,
    const float* __restrict__ B, int ldB, float cB,
    const float* __restrict__ bias, float* __restrict__ out, int ldO) {
    constexpr int TPN = F / 4;
    int t = blockIdx.x * blockDim.x + threadIdx.x;
    if (t >= N_NODES * TPN) return;
    int node = t / TPN;
    int f = (t % TPN) * 4;
    const float* sf = src + f;
    int e0 = rp[node], e1 = rp[node + 1];
    float ax = 0.f, ay = 0.f, az = 0.f, aw = 0.f;
    int j = e0;
    for (; j + 1 < e1; j += 2) {
        int c0 = ci[j], c1 = ci[j + 1];
        float w0 = cw[j], w1 = cw[j + 1];
        float4 v0 = *(const float4*)(sf + (size_t)c0 * ld_s);
        float4 v1 = *(const float4*)(sf + (size_t)c1 * ld_s);
        ax += w0 * v0.x + w1 * v1.x;
        ay += w0 * v0.y + w1 * v1.y;
        az += w0 * v0.z + w1 * v1.z;
        aw += w0 * v0.w + w1 * v1.w;
    }
    if (j < e1) {
        int c0 = ci[j];
        float w0 = cw[j];
        float4 v0 = *(const float4*)(sf + (size_t)c0 * ld_s);
        ax += w0 * v0.x;
        ay += w0 * v0.y;
        az += w0 * v0.z;
        aw += w0 * v0.w;
    }
    float rx = alpha * ax, ry = alpha * ay, rz = alpha * az, rw = alpha * aw;
    if (HAS_A) {
        float4 a4 = *(const float4*)(A + (size_t)node * ldA + f);
        rx += cA * a4.x; ry += cA * a4.y; rz += cA * a4.z; rw += cA * a4.w;
    }
    if (HAS_B) {
        float4 b4 = *(const float4*)(B + (size_t)node * ldB + f);
        rx += cB * b4.x; ry += cB * b4.y; rz += cB * b4.z; rw += cB * b4.w;
    }
    if (RELU) {
        float4 bb = *(const float4*)(bias + f);
        rx = fmaxf(rx + bb.x, 0.f); ry = fmaxf(ry + bb.y, 0.f);
        rz = fmaxf(rz + bb.z, 0.f); rw = fmaxf(rw + bb.w, 0.f);
    }
    *(float4*)(out + (size_t)node * ldO + f) = make_float4(rx, ry, rz, rw);
}

// ---------------- dense matmul: out[N,FOUT] = [A0|A1][N,FIN] @ W[FIN,FOUT] (+bias,relu) --------
// A0: first F0 cols, ld F0 (zero-padded past F0 if !DUAL and FIN tail). A1: cols F0..FIN, ld FIN-F0.

template <int FIN, int F0, int FOUT, bool DUAL, bool RELU>
__global__ __launch_bounds__(256) void matmul2(const float* __restrict__ A0,
                                               const float* __restrict__ A1,
                                               const float* __restrict__ W,
                                               const float* __restrict__ bias,
                                               float* __restrict__ out) {
    constexpr int TN = FOUT / 16;
    constexpr int KC = 16;
    constexpr int LD1 = (FIN - F0) > 0 ? (FIN - F0) : 1;
    __shared__ float lds_a[KC][64 + 4];
    __shared__ float lds_w[KC][FOUT];
    int tid = threadIdx.x;
    int tr = tid >> 4;
    int tc = tid & 15;
    int node0 = blockIdx.x * 64;

    float acc[4][TN];
#pragma unroll
    for (int i = 0; i < 4; ++i)
#pragma unroll
        for (int j = 0; j < TN; ++j) acc[i][j] = 0.0f;

    for (int k0 = 0; k0 < FIN; k0 += KC) {
#pragma unroll
        for (int i = 0; i < 4; ++i) {
            int flat = tid + i * 256;
            int nn = flat >> 4, kk = flat & 15;
            int gn = node0 + nn, gk = k0 + kk;
            float v = 0.0f;
            if (gn < N_NODES) {
                if (gk < F0)
                    v = A0[(size_t)gn * F0 + gk];
                else if (DUAL && gk < FIN)
                    v = A1[(size_t)gn * LD1 + (gk - F0)];
            }
            lds_a[kk][nn] = v;
        }
        constexpr int WTOT = KC * FOUT;
#pragma unroll
        for (int i = 0; i < WTOT / 256; ++i) {
            int flat = tid + i * 256;
            int kk = flat / FOUT, ff = flat % FOUT;
            int gk = k0 + kk;
            lds_w[kk][ff] = (gk < FIN) ? W[(size_t)gk * FOUT + ff] : 0.0f;
        }
        __syncthreads();
#pragma unroll
        for (int k = 0; k < KC; ++k) {
            float4 a = *(const float4*)&lds_a[k][tr * 4];
            float av[4] = {a.x, a.y, a.z, a.w};
            float w[TN];
#pragma unroll
            for (int j = 0; j < TN; ++j) w[j] = lds_w[k][tc * TN + j];
#pragma unroll
            for (int i = 0; i < 4; ++i)
#pragma unroll
                for (int j = 0; j < TN; ++j) acc[i][j] += av[i] * w[j];
        }
        __syncthreads();
    }
#pragma unroll
    for (int i = 0; i < 4; ++i) {
        int gn = node0 + tr * 4 + i;
        if (gn < N_NODES) {
#pragma unroll
            for (int j = 0; j < TN; ++j) {
                int col = tc * TN + j;
                float r = acc[i][j];
                if (RELU) r = fmaxf(r + bias[col], 0.f);
                out[(size_t)gn * FOUT + col] = r;
            }
        }
    }
}

// ---------------- pooling + linear + log_softmax ----------------

__global__ void pool_head_kernel(const float* __restrict__ h, const int* __restrict__ batch,
                                 const float* __restrict__ lw, const float* __restrict__ lb,
                                 float* __restrict__ out) {
    int g = blockIdx.x;
    int f = threadIdx.x;
    int s, e;
    {
        int lo = 0, hi = N_NODES;
        while (lo < hi) { int mid = (lo + hi) >> 1; if (batch[mid] < g) lo = mid + 1; else hi = mid; }
        s = lo;
        hi = N_NODES;
        while (lo < hi) { int mid = (lo + hi) >> 1; if (batch[mid] < g + 1) lo = mid + 1; else hi = mid; }
        e = lo;
    }
    float sum = 0.0f;
    for (int i = s; i < e; ++i) sum += h[(size_t)i * 128 + f];
    float cnt = (float)(e - s);
    float pooled = sum / fmaxf(cnt, 1.0f);

    __shared__ float l0[128], l1[128];
    l0[f] = pooled * lw[f * 2 + 0];
    l1[f] = pooled * lw[f * 2 + 1];
    __syncthreads();
    for (int sdt = 64; sdt > 0; sdt >>= 1) {
        if (f < sdt) { l0[f] += l0[f + sdt]; l1[f] += l1[f + sdt]; }
        __syncthreads();
    }
    if (f == 0) {
        float a = l0[0] + lb[0], b = l1[0] + lb[1];
        float m = fmaxf(a, b);
        float lse = m + logf(expf(a - m) + expf(b - m));
        out[g * 2 + 0] = a - lse;
        out[g * 2 + 1] = b - lse;
    }
}

// ---------------- forward-recurrence layer (layers 2-5) ----------------
// h [N,F] -> Z[N,4F] (T1..T4), then out = [h|Z] @ Wflat[5F,FOUT] + b, relu.

template <int F, int FOUT>
static void run_layer_fwd(const float* h, float* Z, float* hout, const float* W, const float* b,
                          const int* rp, const int* ci, const float* cw, hipStream_t s) {
    constexpr int TPN = F / 4;
    int sp_grid = cdiv(N_NODES * TPN, 256);
    int mm_grid = cdiv(N_NODES, 64);
    const float* np_ = nullptr;
    // Z1 = L h
    spmm_fused<F, false, false, false><<<sp_grid, 256, 0, s>>>(
        rp, ci, cw, h, F, 1.f, np_, 0, 0.f, np_, 0, 0.f, np_, Z + 0 * F, 4 * F);
    // Z2 = 2 L Z1 - h
    spmm_fused<F, true, false, false><<<sp_grid, 256, 0, s>>>(
        rp, ci, cw, Z + 0 * F, 4 * F, 2.f, h, F, -1.f, np_, 0, 0.f, np_, Z + 1 * F, 4 * F);
    // Z3 = 2 L Z2 - Z1
    spmm_fused<F, true, false, false><<<sp_grid, 256, 0, s>>>(
        rp, ci, cw, Z + 1 * F, 4 * F, 2.f, Z + 0 * F, 4 * F, -1.f, np_, 0, 0.f, np_, Z + 2 * F, 4 * F);
    // Z4 = 2 L Z3 - Z2
    spmm_fused<F, true, false, false><<<sp_grid, 256, 0, s>>>(
        rp, ci, cw, Z + 2 * F, 4 * F, 2.f, Z + 1 * F, 4 * F, -1.f, np_, 0, 0.f, np_, Z + 3 * F, 4 * F);
    // out = [h|Z] @ W + b, relu
    matmul2<5 * F, F, FOUT, true, true><<<mm_grid, 256, 0, s>>>(h, Z, W, b, hout);
}

extern "C" void kernel_launch(void* const* d_in, const int* in_sizes, int n_in,
                              void* d_out, int out_size, void* d_ws, size_t ws_size,
                              hipStream_t stream) {
    const float* x = (const float*)d_in[0];
    const int* ei = (const int*)d_in[1];
    const int* batch = (const int*)d_in[2];
    const float* W1 = (const float*)d_in[3];
    const float* b1 = (const float*)d_in[4];
    const float* W2 = (const float*)d_in[5];
    const float* b2 = (const float*)d_in[6];
    const float* W3 = (const float*)d_in[7];
    const float* b3 = (const float*)d_in[8];
    const float* W4 = (const float*)d_in[9];
    const float* b4 = (const float*)d_in[10];
    const float* W5 = (const float*)d_in[11];
    const float* b5 = (const float*)d_in[12];
    const float* lin_w = (const float*)d_in[13];
    const float* lin_b = (const float*)d_in[14];
    const int* row = ei;
    const int* col = ei + N_EDGES;
    float* out = (float*)d_out;

    char* p = (char*)d_ws;
    auto alloc = [&](size_t bytes) {
        char* r = p;
        p += (bytes + 255) & ~(size_t)255;
        return r;
    };
    int* cnt = (int*)alloc((size_t)N_NODES * 4);
    int* rp = (int*)alloc((size_t)(N_NODES + 1) * 4);
    int* cursor = (int*)alloc((size_t)N_NODES * 4);
    float* dinv = (float*)alloc((size_t)N_NODES * 4);
    int* ci = (int*)alloc((size_t)N_EDGES * 4);
    float* cw = (float*)alloc((size_t)N_EDGES * 4);
    float* big = (float*)alloc((size_t)N_NODES * 256 * 4);  // U [N,160] then Z up to [N,256]
    float* hA = (float*)alloc((size_t)N_NODES * 128 * 4);
    float* hB = (float*)alloc((size_t)N_NODES * 128 * 4);
    float* Wc1 = (float*)alloc((size_t)116 * 160 * 4);

    hipMemsetAsync(cnt, 0, (size_t)N_NODES * 4, stream);
    count_kernel<<<cdiv(N_EDGES, 256), 256, 0, stream>>>(row, cnt, N_EDGES);
    scan_kernel<<<1, 1024, 0, stream>>>(cnt, rp, N_NODES);
    dinv_cursor_kernel<<<cdiv(N_NODES, 256), 256, 0, stream>>>(cnt, rp, dinv, cursor, N_NODES);
    fill_kernel<<<cdiv(N_EDGES, 256), 256, 0, stream>>>(row, col, dinv, cursor, ci, cw, N_EDGES);
    repack_w1<<<cdiv(5 * 116 * 32, 256), 256, 0, stream>>>(W1, Wc1);

    // ---- Layer 1 via Clenshaw in 32-dim space ----
    // U[n, k*32+fo] = (x @ W1[k])[n,fo]
    float* U = big;
    matmul2<116, 116, 160, false, false><<<cdiv(N_NODES, 64), 256, 0, stream>>>(
        x, nullptr, Wc1, nullptr, U);
    float* B3 = hB;
    float* B2 = hB + (size_t)N_NODES * 32;
    float* B1 = hB + (size_t)N_NODES * 64;
    float* h1 = hA;  // [N,32]
    const float* np_ = nullptr;
    int g32 = cdiv(N_NODES * 8, 256);
    // B3 = 2 L U4 + U3
    spmm_fused<32, true, false, false><<<g32, 256, 0, stream>>>(
        rp, ci, cw, U + 128, 160, 2.f, U + 96, 160, 1.f, np_, 0, 0.f, np_, B3, 32);
    // B2 = 2 L B3 + U2 - U4
    spmm_fused<32, true, true, false><<<g32, 256, 0, stream>>>(
        rp, ci, cw, B3, 32, 2.f, U + 64, 160, 1.f, U + 128, 160, -1.f, np_, B2, 32);
    // B1 = 2 L B2 + U1 - B3
    spmm_fused<32, true, true, false><<<g32, 256, 0, stream>>>(
        rp, ci, cw, B2, 32, 2.f, U + 32, 160, 1.f, B3, 32, -1.f, np_, B1, 32);
    // h1 = relu( L B1 + U0 - B2 + b1 )
    spmm_fused<32, true, true, true><<<g32, 256, 0, stream>>>(
        rp, ci, cw, B1, 32, 1.f, U + 0, 160, 1.f, B2, 32, -1.f, b1, h1, 32);

    // ---- Layers 2-5 forward recurrence + single fused matmul ----
    float* Z = big;
    float* h2 = hB;  // [N,32] (B buffers dead)
    run_layer_fwd<32, 32>(h1, Z, h2, W2, b2, rp, ci, cw, stream);
    float* h3 = hA;  // [N,64]
    run_layer_fwd<32, 64>(h2, Z, h3, W3, b3, rp, ci, cw, stream);
    float* h4 = hB;  // [N,64]
    run_layer_fwd<64, 64>(h3, Z, h4, W4, b4, rp, ci, cw, stream);
    float* h5 = hA;  // [N,128]
    run_layer_fwd<64, 128>(h4, Z, h5, W5, b5, rp, ci, cw, stream);

    pool_head_kernel<<<N_GRAPHS, 128, 0, stream>>>(h5, batch, lin_w, lin_b, out);
}

// Round 5
// 991.878 us; speedup vs baseline: 2.3393x; 1.0748x over previous
//
#include <hip/hip_runtime.h>

#define N_NODES 50000
#define N_GRAPHS 500
#define N_EDGES 800000

static inline int cdiv(int a, int b) { return (a + b - 1) / b; }

// ---------------- CSR build ----------------

__global__ void count_kernel(const int* __restrict__ row, int* __restrict__ cnt, int e) {
    int t = blockIdx.x * blockDim.x + threadIdx.x;
    if (t < e) atomicAdd(&cnt[row[t]], 1);
}

// Single-block exclusive scan of cnt[0..n) -> rp[0..n].
__global__ void scan_kernel(const int* __restrict__ cnt, int* __restrict__ rp, int n) {
    const int T = 1024, VPT = 8, CHUNK = T * VPT;
    __shared__ int buf[2][1024];
    __shared__ int carry_s;
    int t = threadIdx.x;
    if (t == 0) carry_s = 0;
    __syncthreads();
    for (int base = 0; base < n; base += CHUNK) {
        int v[VPT];
        int lsum = 0;
#pragma unroll
        for (int i = 0; i < VPT; ++i) {
            int idx = base + t * VPT + i;
            v[i] = (idx < n) ? cnt[idx] : 0;
            lsum += v[i];
        }
        buf[0][t] = lsum;
        __syncthreads();
        int src = 0;
#pragma unroll
        for (int off = 1; off < 1024; off <<= 1) {
            int val = buf[src][t];
            if (t >= off) val += buf[src][t - off];
            buf[src ^ 1][t] = val;
            src ^= 1;
            __syncthreads();
        }
        int inc = buf[src][t];
        int carry = carry_s;
        __syncthreads();
        int run = carry + inc - lsum;
#pragma unroll
        for (int i = 0; i < VPT; ++i) {
            int idx = base + t * VPT + i;
            if (idx < n) rp[idx] = run;
            run += v[i];
        }
        if (t == T - 1) carry_s = carry + inc;
        __syncthreads();
    }
    if (t == 0) rp[n] = carry_s;
}

__global__ void dinv_cursor_kernel(const int* __restrict__ cnt, const int* __restrict__ rp,
                                   float* __restrict__ dinv, int* __restrict__ cursor, int n) {
    int t = blockIdx.x * blockDim.x + threadIdx.x;
    if (t < n) {
        int c = cnt[t];
        dinv[t] = (c > 0) ? rsqrtf((float)c) : 0.0f;
        cursor[t] = rp[t];
    }
}

__global__ void fill_kernel(const int* __restrict__ row, const int* __restrict__ col,
                            const float* __restrict__ dinv, int* __restrict__ cursor,
                            int* __restrict__ ci, float* __restrict__ cw, int e) {
    int t = blockIdx.x * blockDim.x + threadIdx.x;
    if (t < e) {
        int r = row[t], c = col[t];
        int slot = atomicAdd(&cursor[r], 1);
        ci[slot] = c;
        cw[slot] = -dinv[r] * dinv[c];
    }
}

// Repack W1 [5][116][32] -> Wc [116][160], Wc[fin][k*32+fo] = W1[k][fin][fo]
__global__ void repack_w1(const float* __restrict__ W, float* __restrict__ Wc) {
    int t = blockIdx.x * blockDim.x + threadIdx.x;
    if (t < 5 * 116 * 32) {
        int k = t / (116 * 32);
        int r = t % (116 * 32);
        int fin = r / 32, fo = r % 32;
        Wc[fin * 160 + k * 32 + fo] = W[t];
    }
}

// ---------------- fused SpMM: out = alpha*L(src) + cA*A + cB*B (+bias,relu) ----------------
// 4-way unrolled gathers for memory-level parallelism (latency-bound kernel).

template <int F, bool HAS_A, bool HAS_B, bool RELU>
__global__ __launch_bounds__(256) void spmm_fused(
    const int* __restrict__ rp, const int* __restrict__ ci, const float* __restrict__ cw,
    const float* __restrict__ src, int ld_s, float alpha,
    const float* __restrict__ A, int ldA, float cA,
    const float* __restrict__ B, int ldB, float cB,
    const float* __restrict__ bias, float* __restrict__ out, int ldO) {
    constexpr int TPN = F / 4;
    int t = blockIdx.x * blockDim.x + threadIdx.x;
    if (t >= N_NODES * TPN) return;
    int node = t / TPN;
    int f = (t % TPN) * 4;
    const float* sf = src + f;
    int e0 = rp[node], e1 = rp[node + 1];
    float ax = 0.f, ay = 0.f, az = 0.f, aw = 0.f;
    int j = e0;
    for (; j + 3 < e1; j += 4) {
        int c0 = ci[j], c1 = ci[j + 1], c2 = ci[j + 2], c3 = ci[j + 3];
        float w0 = cw[j], w1 = cw[j + 1], w2 = cw[j + 2], w3 = cw[j + 3];
        float4 v0 = *(const float4*)(sf + (size_t)c0 * ld_s);
        float4 v1 = *(const float4*)(sf + (size_t)c1 * ld_s);
        float4 v2 = *(const float4*)(sf + (size_t)c2 * ld_s);
        float4 v3 = *(const float4*)(sf + (size_t)c3 * ld_s);
        ax += w0 * v0.x + w1 * v1.x + w2 * v2.x + w3 * v3.x;
        ay += w0 * v0.y + w1 * v1.y + w2 * v2.y + w3 * v3.y;
        az += w0 * v0.z + w1 * v1.z + w2 * v2.z + w3 * v3.z;
        aw += w0 * v0.w + w1 * v1.w + w2 * v2.w + w3 * v3.w;
    }
    for (; j < e1; ++j) {
        int c0 = ci[j];
        float w0 = cw[j];
        float4 v0 = *(const float4*)(sf + (size_t)c0 * ld_s);
        ax += w0 * v0.x;
        ay += w0 * v0.y;
        az += w0 * v0.z;
        aw += w0 * v0.w;
    }
    float rx = alpha * ax, ry = alpha * ay, rz = alpha * az, rw = alpha * aw;
    if (HAS_A) {
        float4 a4 = *(const float4*)(A + (size_t)node * ldA + f);
        rx += cA * a4.x; ry += cA * a4.y; rz += cA * a4.z; rw += cA * a4.w;
    }
    if (HAS_B) {
        float4 b4 = *(const float4*)(B + (size_t)node * ldB + f);
        rx += cB * b4.x; ry += cB * b4.y; rz += cB * b4.z; rw += cB * b4.w;
    }
    if (RELU) {
        float4 bb = *(const float4*)(bias + f);
        rx = fmaxf(rx + bb.x, 0.f); ry = fmaxf(ry + bb.y, 0.f);
        rz = fmaxf(rz + bb.z, 0.f); rw = fmaxf(rw + bb.w, 0.f);
    }
    *(float4*)(out + (size_t)node * ldO + f) = make_float4(rx, ry, rz, rw);
}

// ---------------- dense matmul v3: out[N,FOUT] = [A0|A1][N,FIN] @ W[FIN,FOUT] (+bias,relu) ----
// BM=128 nodes/block, 256 threads as 16x16: thread (tr,tc) owns nodes tr*8..+7,
// cols {tc+16*j}. W-reads stride-16 floats -> conflict-free for FOUT%32==0.
// A staged transposed in lds_a[16][132] (pad -> 2-way writes, conflict-free b128 reads).

template <int FIN, int F0, int FOUT, bool DUAL, bool RELU>
__global__ __launch_bounds__(256) void matmul3(const float* __restrict__ A0,
                                               const float* __restrict__ A1,
                                               const float* __restrict__ W,
                                               const float* __restrict__ bias,
                                               float* __restrict__ out) {
    constexpr int TN = FOUT / 16;
    constexpr int KC = 16;
    constexpr int LDA = 132;  // 128 + 4 pad
    constexpr int LD1 = (FIN - F0) > 0 ? (FIN - F0) : 1;
    __shared__ float lds_a[KC][LDA];
    __shared__ float lds_w[KC][FOUT];
    int tid = threadIdx.x;
    int tr = tid >> 4;
    int tc = tid & 15;
    int node0 = blockIdx.x * 128;

    float acc[8][TN];
#pragma unroll
    for (int i = 0; i < 8; ++i)
#pragma unroll
        for (int j = 0; j < TN; ++j) acc[i][j] = 0.0f;

    for (int k0 = 0; k0 < FIN; k0 += KC) {
        // stage A transposed: 128 nodes x 16 k = 512 float4 loads, 2 per thread
#pragma unroll
        for (int rep = 0; rep < 2; ++rep) {
            int idx = tid + rep * 256;   // 0..511
            int nn = idx >> 2;           // node 0..127
            int kq = (idx & 3) * 4;      // k sub-offset 0,4,8,12
            int gn = node0 + nn;
            int gk = k0 + kq;
            float4 v = make_float4(0.f, 0.f, 0.f, 0.f);
            if (gn < N_NODES) {
                if (gk + 3 < F0)
                    v = *(const float4*)(A0 + (size_t)gn * F0 + gk);
                else if (DUAL && gk >= F0 && gk + 3 < FIN)
                    v = *(const float4*)(A1 + (size_t)gn * LD1 + (gk - F0));
            }
            lds_a[kq + 0][nn] = v.x;
            lds_a[kq + 1][nn] = v.y;
            lds_a[kq + 2][nn] = v.z;
            lds_a[kq + 3][nn] = v.w;
        }
        // stage W chunk: KC x FOUT
        for (int idx = tid; idx < KC * FOUT / 4; idx += 256) {
            int kk = idx / (FOUT / 4);
            int cq = (idx % (FOUT / 4)) * 4;
            int gk = k0 + kk;
            float4 v = make_float4(0.f, 0.f, 0.f, 0.f);
            if (gk < FIN) v = *(const float4*)(W + (size_t)gk * FOUT + cq);
            *(float4*)&lds_w[kk][cq] = v;
        }
        __syncthreads();
#pragma unroll
        for (int k = 0; k < KC; ++k) {
            float4 a0 = *(const float4*)&lds_a[k][tr * 8];
            float4 a1 = *(const float4*)&lds_a[k][tr * 8 + 4];
            float av[8] = {a0.x, a0.y, a0.z, a0.w, a1.x, a1.y, a1.z, a1.w};
            float wv[TN];
#pragma unroll
            for (int j = 0; j < TN; ++j) wv[j] = lds_w[k][tc + 16 * j];
#pragma unroll
            for (int i = 0; i < 8; ++i)
#pragma unroll
                for (int j = 0; j < TN; ++j) acc[i][j] += av[i] * wv[j];
        }
        __syncthreads();
    }
#pragma unroll
    for (int i = 0; i < 8; ++i) {
        int gn = node0 + tr * 8 + i;
        if (gn < N_NODES) {
#pragma unroll
            for (int j = 0; j < TN; ++j) {
                int col = tc + 16 * j;
                float r = acc[i][j];
                if (RELU) r = fmaxf(r + bias[col], 0.f);
                out[(size_t)gn * FOUT + col] = r;
            }
        }
    }
}

// ---------------- pooling + linear + log_softmax ----------------

__global__ void pool_head_kernel(const float* __restrict__ h, const int* __restrict__ batch,
                                 const float* __restrict__ lw, const float* __restrict__ lb,
                                 float* __restrict__ out) {
    int g = blockIdx.x;
    int f = threadIdx.x;
    int s, e;
    {
        int lo = 0, hi = N_NODES;
        while (lo < hi) { int mid = (lo + hi) >> 1; if (batch[mid] < g) lo = mid + 1; else hi = mid; }
        s = lo;
        hi = N_NODES;
        while (lo < hi) { int mid = (lo + hi) >> 1; if (batch[mid] < g + 1) lo = mid + 1; else hi = mid; }
        e = lo;
    }
    float sum = 0.0f;
    for (int i = s; i < e; ++i) sum += h[(size_t)i * 128 + f];
    float cnt = (float)(e - s);
    float pooled = sum / fmaxf(cnt, 1.0f);

    __shared__ float l0[128], l1[128];
    l0[f] = pooled * lw[f * 2 + 0];
    l1[f] = pooled * lw[f * 2 + 1];
    __syncthreads();
    for (int sdt = 64; sdt > 0; sdt >>= 1) {
        if (f < sdt) { l0[f] += l0[f + sdt]; l1[f] += l1[f + sdt]; }
        __syncthreads();
    }
    if (f == 0) {
        float a = l0[0] + lb[0], b = l1[0] + lb[1];
        float m = fmaxf(a, b);
        float lse = m + logf(expf(a - m) + expf(b - m));
        out[g * 2 + 0] = a - lse;
        out[g * 2 + 1] = b - lse;
    }
}

// ---------------- forward-recurrence layer (layers 2-5) ----------------

template <int F, int FOUT>
static void run_layer_fwd(const float* h, float* Z, float* hout, const float* W, const float* b,
                          const int* rp, const int* ci, const float* cw, hipStream_t s) {
    constexpr int TPN = F / 4;
    int sp_grid = cdiv(N_NODES * TPN, 256);
    int mm_grid = cdiv(N_NODES, 128);
    const float* np_ = nullptr;
    // Z1 = L h
    spmm_fused<F, false, false, false><<<sp_grid, 256, 0, s>>>(
        rp, ci, cw, h, F, 1.f, np_, 0, 0.f, np_, 0, 0.f, np_, Z + 0 * F, 4 * F);
    // Z2 = 2 L Z1 - h
    spmm_fused<F, true, false, false><<<sp_grid, 256, 0, s>>>(
        rp, ci, cw, Z + 0 * F, 4 * F, 2.f, h, F, -1.f, np_, 0, 0.f, np_, Z + 1 * F, 4 * F);
    // Z3 = 2 L Z2 - Z1
    spmm_fused<F, true, false, false><<<sp_grid, 256, 0, s>>>(
        rp, ci, cw, Z + 1 * F, 4 * F, 2.f, Z + 0 * F, 4 * F, -1.f, np_, 0, 0.f, np_, Z + 2 * F, 4 * F);
    // Z4 = 2 L Z3 - Z2
    spmm_fused<F, true, false, false><<<sp_grid, 256, 0, s>>>(
        rp, ci, cw, Z + 2 * F, 4 * F, 2.f, Z + 1 * F, 4 * F, -1.f, np_, 0, 0.f, np_, Z + 3 * F, 4 * F);
    // out = [h|Z] @ W + b, relu
    matmul3<5 * F, F, FOUT, true, true><<<mm_grid, 256, 0, s>>>(h, Z, W, b, hout);
}

extern "C" void kernel_launch(void* const* d_in, const int* in_sizes, int n_in,
                              void* d_out, int out_size, void* d_ws, size_t ws_size,
                              hipStream_t stream) {
    const float* x = (const float*)d_in[0];
    const int* ei = (const int*)d_in[1];
    const int* batch = (const int*)d_in[2];
    const float* W1 = (const float*)d_in[3];
    const float* b1 = (const float*)d_in[4];
    const float* W2 = (const float*)d_in[5];
    const float* b2 = (const float*)d_in[6];
    const float* W3 = (const float*)d_in[7];
    const float* b3 = (const float*)d_in[8];
    const float* W4 = (const float*)d_in[9];
    const float* b4 = (const float*)d_in[10];
    const float* W5 = (const float*)d_in[11];
    const float* b5 = (const float*)d_in[12];
    const float* lin_w = (const float*)d_in[13];
    const float* lin_b = (const float*)d_in[14];
    const int* row = ei;
    const int* col = ei + N_EDGES;
    float* out = (float*)d_out;

    char* p = (char*)d_ws;
    auto alloc = [&](size_t bytes) {
        char* r = p;
        p += (bytes + 255) & ~(size_t)255;
        return r;
    };
    int* cnt = (int*)alloc((size_t)N_NODES * 4);
    int* rp = (int*)alloc((size_t)(N_NODES + 1) * 4);
    int* cursor = (int*)alloc((size_t)N_NODES * 4);
    float* dinv = (float*)alloc((size_t)N_NODES * 4);
    int* ci = (int*)alloc((size_t)N_EDGES * 4);
    float* cw = (float*)alloc((size_t)N_EDGES * 4);
    float* big = (float*)alloc((size_t)N_NODES * 256 * 4);  // U [N,160] then Z up to [N,256]
    float* hA = (float*)alloc((size_t)N_NODES * 128 * 4);
    float* hB = (float*)alloc((size_t)N_NODES * 128 * 4);
    float* Wc1 = (float*)alloc((size_t)116 * 160 * 4);

    hipMemsetAsync(cnt, 0, (size_t)N_NODES * 4, stream);
    count_kernel<<<cdiv(N_EDGES, 256), 256, 0, stream>>>(row, cnt, N_EDGES);
    scan_kernel<<<1, 1024, 0, stream>>>(cnt, rp, N_NODES);
    dinv_cursor_kernel<<<cdiv(N_NODES, 256), 256, 0, stream>>>(cnt, rp, dinv, cursor, N_NODES);
    fill_kernel<<<cdiv(N_EDGES, 256), 256, 0, stream>>>(row, col, dinv, cursor, ci, cw, N_EDGES);
    repack_w1<<<cdiv(5 * 116 * 32, 256), 256, 0, stream>>>(W1, Wc1);

    // ---- Layer 1 via Clenshaw in 32-dim space ----
    float* U = big;
    matmul3<116, 116, 160, false, false><<<cdiv(N_NODES, 128), 256, 0, stream>>>(
        x, nullptr, Wc1, nullptr, U);
    float* B3 = hB;
    float* B2 = hB + (size_t)N_NODES * 32;
    float* B1 = hB + (size_t)N_NODES * 64;
    float* h1 = hA;  // [N,32]
    const float* np_ = nullptr;
    int g32 = cdiv(N_NODES * 8, 256);
    // B3 = 2 L U4 + U3
    spmm_fused<32, true, false, false><<<g32, 256, 0, stream>>>(
        rp, ci, cw, U + 128, 160, 2.f, U + 96, 160, 1.f, np_, 0, 0.f, np_, B3, 32);
    // B2 = 2 L B3 + U2 - U4
    spmm_fused<32, true, true, false><<<g32, 256, 0, stream>>>(
        rp, ci, cw, B3, 32, 2.f, U + 64, 160, 1.f, U + 128, 160, -1.f, np_, B2, 32);
    // B1 = 2 L B2 + U1 - B3
    spmm_fused<32, true, true, false><<<g32, 256, 0, stream>>>(
        rp, ci, cw, B2, 32, 2.f, U + 32, 160, 1.f, B3, 32, -1.f, np_, B1, 32);
    // h1 = relu( L B1 + U0 - B2 + b1 )
    spmm_fused<32, true, true, true><<<g32, 256, 0, stream>>>(
        rp, ci, cw, B1, 32, 1.f, U + 0, 160, 1.f, B2, 32, -1.f, b1, h1, 32);

    // ---- Layers 2-5 forward recurrence + single fused matmul ----
    float* Z = big;
    float* h2 = hB;  // [N,32]
    run_layer_fwd<32, 32>(h1, Z, h2, W2, b2, rp, ci, cw, stream);
    float* h3 = hA;  // [N,64]
    run_layer_fwd<32, 64>(h2, Z, h3, W3, b3, rp, ci, cw, stream);
    float* h4 = hB;  // [N,64]
    run_layer_fwd<64, 64>(h3, Z, h4, W4, b4, rp, ci, cw, stream);
    float* h5 = hA;  // [N,128]
    run_layer_fwd<64, 128>(h4, Z, h5, W5, b5, rp, ci, cw, stream);

    pool_head_kernel<<<N_GRAPHS, 128, 0, stream>>>(h5, batch, lin_w, lin_b, out);
}

// Round 7
// 858.159 us; speedup vs baseline: 2.7038x; 1.1558x over previous
//
#include <hip/hip_runtime.h>

#define N_NODES 50000
#define N_GRAPHS 500
#define N_EDGES 800000

static inline int cdiv(int a, int b) { return (a + b - 1) / b; }

typedef __attribute__((ext_vector_type(8))) short short8v;
typedef __attribute__((ext_vector_type(4))) float f32x4;

__device__ __forceinline__ unsigned short f2b(float f) {
    unsigned int u = __builtin_bit_cast(unsigned int, f);
    unsigned int r = (u + 0x7fff + ((u >> 16) & 1)) >> 16;  // RNE
    return (unsigned short)r;
}

// ---------------- CSR build ----------------

__global__ void count_kernel(const int* __restrict__ row, int* __restrict__ cnt, int e) {
    int t = blockIdx.x * blockDim.x + threadIdx.x;
    if (t < e) atomicAdd(&cnt[row[t]], 1);
}

__global__ void scan_kernel(const int* __restrict__ cnt, int* __restrict__ rp, int n) {
    const int T = 1024, VPT = 8, CHUNK = T * VPT;
    __shared__ int buf[2][1024];
    __shared__ int carry_s;
    int t = threadIdx.x;
    if (t == 0) carry_s = 0;
    __syncthreads();
    for (int base = 0; base < n; base += CHUNK) {
        int v[VPT];
        int lsum = 0;
#pragma unroll
        for (int i = 0; i < VPT; ++i) {
            int idx = base + t * VPT + i;
            v[i] = (idx < n) ? cnt[idx] : 0;
            lsum += v[i];
        }
        buf[0][t] = lsum;
        __syncthreads();
        int src = 0;
#pragma unroll
        for (int off = 1; off < 1024; off <<= 1) {
            int val = buf[src][t];
            if (t >= off) val += buf[src][t - off];
            buf[src ^ 1][t] = val;
            src ^= 1;
            __syncthreads();
        }
        int inc = buf[src][t];
        int carry = carry_s;
        __syncthreads();
        int run = carry + inc - lsum;
#pragma unroll
        for (int i = 0; i < VPT; ++i) {
            int idx = base + t * VPT + i;
            if (idx < n) rp[idx] = run;
            run += v[i];
        }
        if (t == T - 1) carry_s = carry + inc;
        __syncthreads();
    }
    if (t == 0) rp[n] = carry_s;
}

__global__ void dinv_cursor_kernel(const int* __restrict__ cnt, const int* __restrict__ rp,
                                   float* __restrict__ dinv, int* __restrict__ cursor, int n) {
    int t = blockIdx.x * blockDim.x + threadIdx.x;
    if (t < n) {
        int c = cnt[t];
        dinv[t] = (c > 0) ? rsqrtf((float)c) : 0.0f;
        cursor[t] = rp[t];
    }
}

__global__ void fill_kernel(const int* __restrict__ row, const int* __restrict__ col,
                            const float* __restrict__ dinv, int* __restrict__ cursor,
                            int* __restrict__ ci, float* __restrict__ cw, int e) {
    int t = blockIdx.x * blockDim.x + threadIdx.x;
    if (t < e) {
        int r = row[t], c = col[t];
        int slot = atomicAdd(&cursor[r], 1);
        ci[slot] = c;
        cw[slot] = -dinv[r] * dinv[c];
    }
}

// ---------------- bf16 conversions ----------------

// x [N,116] f32 -> xb [N,128] bf16 zero-padded
__global__ void conv_x_kernel(const float* __restrict__ x, unsigned short* __restrict__ xb) {
    int t = blockIdx.x * blockDim.x + threadIdx.x;
    if (t >= N_NODES * 128) return;
    int r = t >> 7, c = t & 127;
    xb[t] = (c < 116) ? f2b(x[(size_t)r * 116 + c]) : 0;
}

// W1 [5][116][32] -> wt1 [160][128] bf16, wt1[c][k] = k<116 ? W1[c/32][k][c%32] : 0
__global__ void conv_wt1_kernel(const float* __restrict__ W, unsigned short* __restrict__ wt) {
    int t = blockIdx.x * blockDim.x + threadIdx.x;
    if (t >= 160 * 128) return;
    int c = t >> 7, k = t & 127;
    wt[t] = (k < 116) ? f2b(W[(c >> 5) * (116 * 32) + k * 32 + (c & 31)]) : 0;
}

// W [KB, FOUT] f32 (KB=5F) -> wt [FOUT][KB] bf16 transposed
template <int FOUT, int KB>
__global__ void conv_wt_kernel(const float* __restrict__ W, unsigned short* __restrict__ wt) {
    int t = blockIdx.x * blockDim.x + threadIdx.x;
    if (t >= FOUT * KB) return;
    int c = t / KB, k = t % KB;
    wt[t] = f2b(W[(size_t)k * FOUT + c]);
}

// ---------------- fused SpMM: out = alpha*L(src) + cA*A + cB*B (+bias,relu) ----------------
// optional bf16 co-output (matmul A operand)

template <int F, bool HAS_A, bool HAS_B, bool RELU, bool WBF>
__global__ __launch_bounds__(256) void spmm_fused(
    const int* __restrict__ rp, const int* __restrict__ ci, const float* __restrict__ cw,
    const float* __restrict__ src, int ld_s, float alpha,
    const float* __restrict__ A, int ldA, float cA,
    const float* __restrict__ B, int ldB, float cB,
    const float* __restrict__ bias, float* __restrict__ out, int ldO,
    unsigned short* __restrict__ outb) {
    constexpr int TPN = F / 4;
    int t = blockIdx.x * blockDim.x + threadIdx.x;
    if (t >= N_NODES * TPN) return;
    int node = t / TPN;
    int f = (t % TPN) * 4;
    const float* sf = src + f;
    int e0 = rp[node], e1 = rp[node + 1];
    float ax = 0.f, ay = 0.f, az = 0.f, aw = 0.f;
    int j = e0;
    for (; j + 3 < e1; j += 4) {
        int c0 = ci[j], c1 = ci[j + 1], c2 = ci[j + 2], c3 = ci[j + 3];
        float w0 = cw[j], w1 = cw[j + 1], w2 = cw[j + 2], w3 = cw[j + 3];
        float4 v0 = *(const float4*)(sf + (size_t)c0 * ld_s);
        float4 v1 = *(const float4*)(sf + (size_t)c1 * ld_s);
        float4 v2 = *(const float4*)(sf + (size_t)c2 * ld_s);
        float4 v3 = *(const float4*)(sf + (size_t)c3 * ld_s);
        ax += w0 * v0.x + w1 * v1.x + w2 * v2.x + w3 * v3.x;
        ay += w0 * v0.y + w1 * v1.y + w2 * v2.y + w3 * v3.y;
        az += w0 * v0.z + w1 * v1.z + w2 * v2.z + w3 * v3.z;
        aw += w0 * v0.w + w1 * v1.w + w2 * v2.w + w3 * v3.w;
    }
    for (; j < e1; ++j) {
        int c0 = ci[j];
        float w0 = cw[j];
        float4 v0 = *(const float4*)(sf + (size_t)c0 * ld_s);
        ax += w0 * v0.x;
        ay += w0 * v0.y;
        az += w0 * v0.z;
        aw += w0 * v0.w;
    }
    float rx = alpha * ax, ry = alpha * ay, rz = alpha * az, rw = alpha * aw;
    if (HAS_A) {
        float4 a4 = *(const float4*)(A + (size_t)node * ldA + f);
        rx += cA * a4.x; ry += cA * a4.y; rz += cA * a4.z; rw += cA * a4.w;
    }
    if (HAS_B) {
        float4 b4 = *(const float4*)(B + (size_t)node * ldB + f);
        rx += cB * b4.x; ry += cB * b4.y; rz += cB * b4.z; rw += cB * b4.w;
    }
    if (RELU) {
        float4 bb = *(const float4*)(bias + f);
        rx = fmaxf(rx + bb.x, 0.f); ry = fmaxf(ry + bb.y, 0.f);
        rz = fmaxf(rz + bb.z, 0.f); rw = fmaxf(rw + bb.w, 0.f);
    }
    *(float4*)(out + (size_t)node * ldO + f) = make_float4(rx, ry, rz, rw);
    if (WBF) {
        ushort4 b4;
        b4.x = f2b(rx); b4.y = f2b(ry); b4.z = f2b(rz); b4.w = f2b(rw);
        *(ushort4*)(outb + (size_t)node * ldO + f) = b4;
    }
}

// ---------------- MFMA matmul: out[N,FOUT] = [A0b|A1b][N,KB] @ Wt^T (+bias,relu) -------------
// LDS-free. 256 thr = 4 waves; BM=64 (wave w owns rows blk*64 + w*16 .. +15).
// A-frag: lane l loads 8 contiguous bf16 at row (l&15), k = k0 + (l>>4)*8, direct from global.
// B-frag: Wt is [FOUT][KB] bf16 (pre-transposed); lane l loads 8 bf16 at col-row (ct*16 + (l&15)).
// Any shared per-lane k-permutation between A and B frags cancels in the dot product.
// C/D: col = lane&15, row = (lane>>4)*4 + reg  [verified layout].

template <int KB, int F0, int FOUT, bool DUAL, bool RELU, bool WBF>
__global__ __launch_bounds__(256) void mm_mfma(const unsigned short* __restrict__ A0b,
                                               const unsigned short* __restrict__ A1b,
                                               const unsigned short* __restrict__ Wt,
                                               const float* __restrict__ bias,
                                               float* __restrict__ out,
                                               unsigned short* __restrict__ outb) {
    constexpr int NT = FOUT / 16;
    constexpr int LD1 = (KB - F0) > 0 ? (KB - F0) : 1;
    int tid = threadIdx.x;
    int l = tid & 63;
    int w = tid >> 6;
    int row0 = blockIdx.x * 64 + w * 16;
    int r15 = l & 15;
    int kg = l >> 4;
    int rr = row0 + r15;
    if (rr > N_NODES - 1) rr = N_NODES - 1;  // clamp; stores are guarded

    f32x4 acc[NT];
#pragma unroll
    for (int ct = 0; ct < NT; ++ct) acc[ct] = (f32x4){0.f, 0.f, 0.f, 0.f};

    for (int k0 = 0; k0 < KB; k0 += 32) {
        int kl = k0 + kg * 8;
        const unsigned short* ap;
        if (!DUAL || k0 < F0)
            ap = A0b + (size_t)rr * F0 + kl;
        else
            ap = A1b + (size_t)rr * LD1 + (kl - F0);
        short8v af = *(const short8v*)ap;
#pragma unroll
        for (int ct = 0; ct < NT; ++ct) {
            const unsigned short* bp = Wt + (size_t)(ct * 16 + r15) * KB + kl;
            short8v bf = *(const short8v*)bp;
            acc[ct] = __builtin_amdgcn_mfma_f32_16x16x32_bf16(af, bf, acc[ct], 0, 0, 0);
        }
    }

    int orow = row0 + kg * 4;
#pragma unroll
    for (int ct = 0; ct < NT; ++ct) {
        int col = ct * 16 + r15;
        float bv = RELU ? bias[col] : 0.f;
#pragma unroll
        for (int i = 0; i < 4; ++i) {
            int rw = orow + i;
            if (rw < N_NODES) {
                float v = acc[ct][i];
                if (RELU) v = fmaxf(v + bv, 0.f);
                out[(size_t)rw * FOUT + col] = v;
                if (WBF) outb[(size_t)rw * FOUT + col] = f2b(v);
            }
        }
    }
}

// ---------------- pooling + linear + log_softmax ----------------

__global__ void pool_head_kernel(const float* __restrict__ h, const int* __restrict__ batch,
                                 const float* __restrict__ lw, const float* __restrict__ lb,
                                 float* __restrict__ out) {
    int g = blockIdx.x;
    int f = threadIdx.x;
    int s, e;
    {
        int lo = 0, hi = N_NODES;
        while (lo < hi) { int mid = (lo + hi) >> 1; if (batch[mid] < g) lo = mid + 1; else hi = mid; }
        s = lo;
        hi = N_NODES;
        while (lo < hi) { int mid = (lo + hi) >> 1; if (batch[mid] < g + 1) lo = mid + 1; else hi = mid; }
        e = lo;
    }
    float sum = 0.0f;
    for (int i = s; i < e; ++i) sum += h[(size_t)i * 128 + f];
    float cnt = (float)(e - s);
    float pooled = sum / fmaxf(cnt, 1.0f);

    __shared__ float l0[128], l1[128];
    l0[f] = pooled * lw[f * 2 + 0];
    l1[f] = pooled * lw[f * 2 + 1];
    __syncthreads();
    for (int sdt = 64; sdt > 0; sdt >>= 1) {
        if (f < sdt) { l0[f] += l0[f + sdt]; l1[f] += l1[f + sdt]; }
        __syncthreads();
    }
    if (f == 0) {
        float a = l0[0] + lb[0], b = l1[0] + lb[1];
        float m = fmaxf(a, b);
        float lse = m + logf(expf(a - m) + expf(b - m));
        out[g * 2 + 0] = a - lse;
        out[g * 2 + 1] = b - lse;
    }
}

// ---------------- forward-recurrence layer (layers 2-5) ----------------
// h [N,F] fp32 (+hb bf16) -> Z fp32/Zb bf16 [N,4F], then MFMA matmul.

template <int F, int FOUT, bool WBF_OUT>
static void run_layer_fwd(const float* h, const unsigned short* hb, float* Z, unsigned short* Zb,
                          float* hout, unsigned short* houtb, const unsigned short* Wt,
                          const float* b, const int* rp, const int* ci, const float* cw,
                          hipStream_t s) {
    constexpr int TPN = F / 4;
    int sp_grid = cdiv(N_NODES * TPN, 256);
    int mm_grid = cdiv(N_NODES, 64);
    const float* np_ = nullptr;
    // Z1 = L h
    spmm_fused<F, false, false, false, true><<<sp_grid, 256, 0, s>>>(
        rp, ci, cw, h, F, 1.f, np_, 0, 0.f, np_, 0, 0.f, np_, Z + 0 * F, 4 * F, Zb + 0 * F);
    // Z2 = 2 L Z1 - h
    spmm_fused<F, true, false, false, true><<<sp_grid, 256, 0, s>>>(
        rp, ci, cw, Z + 0 * F, 4 * F, 2.f, h, F, -1.f, np_, 0, 0.f, np_, Z + 1 * F, 4 * F, Zb + 1 * F);
    // Z3 = 2 L Z2 - Z1
    spmm_fused<F, true, false, false, true><<<sp_grid, 256, 0, s>>>(
        rp, ci, cw, Z + 1 * F, 4 * F, 2.f, Z + 0 * F, 4 * F, -1.f, np_, 0, 0.f, np_, Z + 2 * F, 4 * F, Zb + 2 * F);
    // Z4 = 2 L Z3 - Z2
    spmm_fused<F, true, false, false, true><<<sp_grid, 256, 0, s>>>(
        rp, ci, cw, Z + 2 * F, 4 * F, 2.f, Z + 1 * F, 4 * F, -1.f, np_, 0, 0.f, np_, Z + 3 * F, 4 * F, Zb + 3 * F);
    // out = [hb|Zb] @ W + b, relu (bf16 MFMA, fp32 accum)
    mm_mfma<5 * F, F, FOUT, true, true, WBF_OUT><<<mm_grid, 256, 0, s>>>(hb, Zb, Wt, b, hout, houtb);
}

extern "C" void kernel_launch(void* const* d_in, const int* in_sizes, int n_in,
                              void* d_out, int out_size, void* d_ws, size_t ws_size,
                              hipStream_t stream) {
    const float* x = (const float*)d_in[0];
    const int* ei = (const int*)d_in[1];
    const int* batch = (const int*)d_in[2];
    const float* W1 = (const float*)d_in[3];
    const float* b1 = (const float*)d_in[4];
    const float* W2 = (const float*)d_in[5];
    const float* b2 = (const float*)d_in[6];
    const float* W3 = (const float*)d_in[7];
    const float* b3 = (const float*)d_in[8];
    const float* W4 = (const float*)d_in[9];
    const float* b4 = (const float*)d_in[10];
    const float* W5 = (const float*)d_in[11];
    const float* b5 = (const float*)d_in[12];
    const float* lin_w = (const float*)d_in[13];
    const float* lin_b = (const float*)d_in[14];
    const int* row = ei;
    const int* col = ei + N_EDGES;
    float* out = (float*)d_out;

    char* p = (char*)d_ws;
    auto alloc = [&](size_t bytes) {
        char* r = p;
        p += (bytes + 255) & ~(size_t)255;
        return r;
    };
    int* cnt = (int*)alloc((size_t)N_NODES * 4);
    int* rp = (int*)alloc((size_t)(N_NODES + 1) * 4);
    int* cursor = (int*)alloc((size_t)N_NODES * 4);
    float* dinv = (float*)alloc((size_t)N_NODES * 4);
    int* ci = (int*)alloc((size_t)N_EDGES * 4);
    float* cw = (float*)alloc((size_t)N_EDGES * 4);
    float* big = (float*)alloc((size_t)N_NODES * 256 * 4);  // U [N,160] then Z [N,256]
    float* hA = (float*)alloc((size_t)N_NODES * 128 * 4);
    float* hB = (float*)alloc((size_t)N_NODES * 128 * 4);
    unsigned short* bfA = (unsigned short*)alloc((size_t)N_NODES * 128 * 2);  // h1b/h3b
    unsigned short* bfB = (unsigned short*)alloc((size_t)N_NODES * 128 * 2);  // xb, h2b/h4b
    unsigned short* Zb = (unsigned short*)alloc((size_t)N_NODES * 256 * 2);
    unsigned short* wt1 = (unsigned short*)alloc((size_t)160 * 128 * 2);
    unsigned short* wt2 = (unsigned short*)alloc((size_t)32 * 160 * 2);
    unsigned short* wt3 = (unsigned short*)alloc((size_t)64 * 160 * 2);
    unsigned short* wt4 = (unsigned short*)alloc((size_t)64 * 320 * 2);
    unsigned short* wt5 = (unsigned short*)alloc((size_t)128 * 320 * 2);

    hipMemsetAsync(cnt, 0, (size_t)N_NODES * 4, stream);
    count_kernel<<<cdiv(N_EDGES, 256), 256, 0, stream>>>(row, cnt, N_EDGES);
    scan_kernel<<<1, 1024, 0, stream>>>(cnt, rp, N_NODES);
    dinv_cursor_kernel<<<cdiv(N_NODES, 256), 256, 0, stream>>>(cnt, rp, dinv, cursor, N_NODES);
    fill_kernel<<<cdiv(N_EDGES, 256), 256, 0, stream>>>(row, col, dinv, cursor, ci, cw, N_EDGES);

    // bf16 prep
    conv_x_kernel<<<cdiv(N_NODES * 128, 256), 256, 0, stream>>>(x, bfB);
    conv_wt1_kernel<<<cdiv(160 * 128, 256), 256, 0, stream>>>(W1, wt1);
    conv_wt_kernel<32, 160><<<cdiv(32 * 160, 256), 256, 0, stream>>>(W2, wt2);
    conv_wt_kernel<64, 160><<<cdiv(64 * 160, 256), 256, 0, stream>>>(W3, wt3);
    conv_wt_kernel<64, 320><<<cdiv(64 * 320, 256), 256, 0, stream>>>(W4, wt4);
    conv_wt_kernel<128, 320><<<cdiv(128 * 320, 256), 256, 0, stream>>>(W5, wt5);

    // ---- Layer 1 via Clenshaw in 32-dim space ----
    // U[n, k*32+fo] = (x @ W1[k])[n,fo]   (MFMA: xb [N,128] @ wt1^T -> [N,160] fp32)
    float* U = big;
    unsigned short* nb_ = nullptr;
    mm_mfma<128, 128, 160, false, false, false><<<cdiv(N_NODES, 64), 256, 0, stream>>>(
        bfB, nb_, wt1, nullptr, U, nb_);
    float* B3 = hB;
    float* B2 = hB + (size_t)N_NODES * 32;
    float* B1 = hB + (size_t)N_NODES * 64;
    float* h1 = hA;  // [N,32]
    const float* np_ = nullptr;
    int g32 = cdiv(N_NODES * 8, 256);
    // B3 = 2 L U4 + U3
    spmm_fused<32, true, false, false, false><<<g32, 256, 0, stream>>>(
        rp, ci, cw, U + 128, 160, 2.f, U + 96, 160, 1.f, np_, 0, 0.f, np_, B3, 32, nb_);
    // B2 = 2 L B3 + U2 - U4
    spmm_fused<32, true, true, false, false><<<g32, 256, 0, stream>>>(
        rp, ci, cw, B3, 32, 2.f, U + 64, 160, 1.f, U + 128, 160, -1.f, np_, B2, 32, nb_);
    // B1 = 2 L B2 + U1 - B3
    spmm_fused<32, true, true, false, false><<<g32, 256, 0, stream>>>(
        rp, ci, cw, B2, 32, 2.f, U + 32, 160, 1.f, B3, 32, -1.f, np_, B1, 32, nb_);
    // h1 = relu( L B1 + U0 - B2 + b1 ), dual-write bf16
    spmm_fused<32, true, true, true, true><<<g32, 256, 0, stream>>>(
        rp, ci, cw, B1, 32, 1.f, U + 0, 160, 1.f, B2, 32, -1.f, b1, h1, 32, bfA);

    // ---- Layers 2-5: fp32 recurrence + bf16 MFMA matmul ----
    float* Z = big;
    // L2: h1(hA,bfA) -> h2(hB,bfB)
    run_layer_fwd<32, 32, true>(h1, bfA, Z, Zb, hB, bfB, wt2, b2, rp, ci, cw, stream);
    // L3: h2(hB,bfB) -> h3(hA,bfA)
    run_layer_fwd<32, 64, true>(hB, bfB, Z, Zb, hA, bfA, wt3, b3, rp, ci, cw, stream);
    // L4: h3(hA,bfA) -> h4(hB,bfB)
    run_layer_fwd<64, 64, true>(hA, bfA, Z, Zb, hB, bfB, wt4, b4, rp, ci, cw, stream);
    // L5: h4(hB,bfB) -> h5(hA), no bf16 out
    run_layer_fwd<64, 128, false>(hB, bfB, Z, Zb, hA, nb_, wt5, b5, rp, ci, cw, stream);

    pool_head_kernel<<<N_GRAPHS, 128, 0, stream>>>(hA, batch, lin_w, lin_b, out);
}

// Round 10
// 744.547 us; speedup vs baseline: 3.1164x; 1.1526x over previous
//
#include <hip/hip_runtime.h>

#define N_NODES 50000
#define N_GRAPHS 500
#define N_EDGES 800000

static inline int cdiv(int a, int b) { return (a + b - 1) / b; }

typedef _Float16 half8v __attribute__((ext_vector_type(8)));
typedef _Float16 half4v __attribute__((ext_vector_type(4)));
typedef __attribute__((ext_vector_type(4))) float f32x4;

__device__ __forceinline__ _Float16 f2h(float f) { return (_Float16)f; }

// ---------------- CSR build ----------------

__global__ void count_kernel(const int* __restrict__ row, int* __restrict__ cnt, int e) {
    int t = blockIdx.x * blockDim.x + threadIdx.x;
    if (t < e) atomicAdd(&cnt[row[t]], 1);
}

// 3-kernel scan: per-block exclusive scan + block sums, scan sums, add offsets.
__global__ void block_scan_kernel(const int* __restrict__ cnt, int* __restrict__ rp,
                                  int* __restrict__ bsum, int n) {
    __shared__ int buf[2][256];
    int t = threadIdx.x;
    int idx = blockIdx.x * 256 + t;
    int v = (idx < n) ? cnt[idx] : 0;
    buf[0][t] = v;
    __syncthreads();
    int s = 0;
#pragma unroll
    for (int off = 1; off < 256; off <<= 1) {
        int x = buf[s][t];
        if (t >= off) x += buf[s][t - off];
        buf[s ^ 1][t] = x;
        s ^= 1;
        __syncthreads();
    }
    if (idx < n) rp[idx] = buf[s][t] - v;  // exclusive within block
    if (t == 255) bsum[blockIdx.x] = buf[s][255];
}

__global__ void scan_bsum_kernel(int* __restrict__ bsum, int nb) {
    __shared__ int buf[2][256];
    int t = threadIdx.x;
    int v = (t < nb) ? bsum[t] : 0;
    buf[0][t] = v;
    __syncthreads();
    int s = 0;
#pragma unroll
    for (int off = 1; off < 256; off <<= 1) {
        int x = buf[s][t];
        if (t >= off) x += buf[s][t - off];
        buf[s ^ 1][t] = x;
        s ^= 1;
        __syncthreads();
    }
    if (t < nb) bsum[t] = buf[s][t] - v;  // exclusive
}

__global__ void add_off_kernel(int* __restrict__ rp, const int* __restrict__ bsum, int n) {
    int idx = blockIdx.x * 256 + threadIdx.x;
    if (idx < n) rp[idx] += bsum[idx >> 8];
    if (idx == 0) rp[n] = N_EDGES;
}

__global__ void dinv_cursor_kernel(const int* __restrict__ cnt, const int* __restrict__ rp,
                                   float* __restrict__ dinv, int* __restrict__ cursor, int n) {
    int t = blockIdx.x * blockDim.x + threadIdx.x;
    if (t < n) {
        int c = cnt[t];
        dinv[t] = (c > 0) ? rsqrtf((float)c) : 0.0f;
        cursor[t] = rp[t];
    }
}

// Packed edge record: .x = col index, .y = weight bits (one 8B scatter store)
__global__ void fill_kernel(const int* __restrict__ row, const int* __restrict__ col,
                            const float* __restrict__ dinv, int* __restrict__ cursor,
                            int2* __restrict__ ew, int e) {
    int t = blockIdx.x * blockDim.x + threadIdx.x;
    if (t < e) {
        int r = row[t], c = col[t];
        int slot = atomicAdd(&cursor[r], 1);
        float w = -dinv[r] * dinv[c];
        ew[slot] = make_int2(c, __float_as_int(w));
    }
}

// ---------------- fp16 conversions ----------------

// x [N,116] f32 -> xh [N,128] fp16 zero-padded
__global__ void conv_x_kernel(const float* __restrict__ x, _Float16* __restrict__ xh) {
    int t = blockIdx.x * blockDim.x + threadIdx.x;
    if (t >= N_NODES * 128) return;
    int r = t >> 7, c = t & 127;
    xh[t] = (c < 116) ? f2h(x[(size_t)r * 116 + c]) : (_Float16)0.f;
}

// W1 [5][116][32] -> wt1 [160][128] fp16, wt1[c][k] = k<116 ? W1[c/32][k][c%32] : 0
__global__ void conv_wt1_kernel(const float* __restrict__ W, _Float16* __restrict__ wt) {
    int t = blockIdx.x * blockDim.x + threadIdx.x;
    if (t >= 160 * 128) return;
    int c = t >> 7, k = t & 127;
    wt[t] = (k < 116) ? f2h(W[(c >> 5) * (116 * 32) + k * 32 + (c & 31)]) : (_Float16)0.f;
}

// W [KB, FOUT] f32 -> wt [FOUT][KB] fp16 transposed
template <int FOUT, int KB>
__global__ void conv_wt_kernel(const float* __restrict__ W, _Float16* __restrict__ wt) {
    int t = blockIdx.x * blockDim.x + threadIdx.x;
    if (t >= FOUT * KB) return;
    int c = t / KB, k = t % KB;
    wt[t] = f2h(W[(size_t)k * FOUT + c]);
}

// ---------------- fused SpMM: out = alpha*L(srch) + cA*A + cB*B (+bias,relu) ----------------
// L gathers fp16 (8B per 4 feats); carry operands A/B stay fp32 (coalesced).
// Writes fp32 out and (optionally) fp16 co-output at the same ldO.

template <int F, bool HAS_A, bool HAS_B, bool RELU, bool WH>
__global__ __launch_bounds__(256) void spmm_fused(
    const int* __restrict__ rp, const int2* __restrict__ ew,
    const _Float16* __restrict__ srch, int ld_s, float alpha,
    const float* __restrict__ A, int ldA, float cA,
    const float* __restrict__ B, int ldB, float cB,
    const float* __restrict__ bias, float* __restrict__ out, int ldO,
    _Float16* __restrict__ outh) {
    constexpr int TPN = F / 4;
    int t = blockIdx.x * blockDim.x + threadIdx.x;
    if (t >= N_NODES * TPN) return;
    int node = t / TPN;
    int f = (t % TPN) * 4;
    const _Float16* sf = srch + f;
    int e0 = rp[node], e1 = rp[node + 1];
    float ax = 0.f, ay = 0.f, az = 0.f, aw = 0.f;
    int j = e0;
    for (; j + 3 < e1; j += 4) {
        int2 ea = ew[j], eb = ew[j + 1], ec = ew[j + 2], ed = ew[j + 3];
        float w0 = __int_as_float(ea.y), w1 = __int_as_float(eb.y);
        float w2 = __int_as_float(ec.y), w3 = __int_as_float(ed.y);
        half4v v0 = *(const half4v*)(sf + (size_t)ea.x * ld_s);
        half4v v1 = *(const half4v*)(sf + (size_t)eb.x * ld_s);
        half4v v2 = *(const half4v*)(sf + (size_t)ec.x * ld_s);
        half4v v3 = *(const half4v*)(sf + (size_t)ed.x * ld_s);
        ax += w0 * (float)v0.x + w1 * (float)v1.x + w2 * (float)v2.x + w3 * (float)v3.x;
        ay += w0 * (float)v0.y + w1 * (float)v1.y + w2 * (float)v2.y + w3 * (float)v3.y;
        az += w0 * (float)v0.z + w1 * (float)v1.z + w2 * (float)v2.z + w3 * (float)v3.z;
        aw += w0 * (float)v0.w + w1 * (float)v1.w + w2 * (float)v2.w + w3 * (float)v3.w;
    }
    for (; j < e1; ++j) {
        int2 ea = ew[j];
        float w0 = __int_as_float(ea.y);
        half4v v0 = *(const half4v*)(sf + (size_t)ea.x * ld_s);
        ax += w0 * (float)v0.x;
        ay += w0 * (float)v0.y;
        az += w0 * (float)v0.z;
        aw += w0 * (float)v0.w;
    }
    float rx = alpha * ax, ry = alpha * ay, rz = alpha * az, rw = alpha * aw;
    if (HAS_A) {
        float4 a4 = *(const float4*)(A + (size_t)node * ldA + f);
        rx += cA * a4.x; ry += cA * a4.y; rz += cA * a4.z; rw += cA * a4.w;
    }
    if (HAS_B) {
        float4 b4 = *(const float4*)(B + (size_t)node * ldB + f);
        rx += cB * b4.x; ry += cB * b4.y; rz += cB * b4.z; rw += cB * b4.w;
    }
    if (RELU) {
        float4 bb = *(const float4*)(bias + f);
        rx = fmaxf(rx + bb.x, 0.f); ry = fmaxf(ry + bb.y, 0.f);
        rz = fmaxf(rz + bb.z, 0.f); rw = fmaxf(rw + bb.w, 0.f);
    }
    *(float4*)(out + (size_t)node * ldO + f) = make_float4(rx, ry, rz, rw);
    if (WH) {
        half4v h4;
        h4.x = f2h(rx); h4.y = f2h(ry); h4.z = f2h(rz); h4.w = f2h(rw);
        *(half4v*)(outh + (size_t)node * ldO + f) = h4;
    }
}

// ---------------- MFMA matmul (fp16): out[N,FOUT] = [A0h|A1h][N,KB] @ Wt^T (+bias,relu) ------
// LDS-free; per-lane k-permutation identical on A and B frags -> cancels.
// C/D: col = lane&15, row = (lane>>4)*4 + reg  [verified layout].

template <int KB, int F0, int FOUT, bool DUAL, bool RELU, bool WH>
__global__ __launch_bounds__(256) void mm_mfma(const _Float16* __restrict__ A0h,
                                               const _Float16* __restrict__ A1h,
                                               const _Float16* __restrict__ Wt,
                                               const float* __restrict__ bias,
                                               float* __restrict__ out,
                                               _Float16* __restrict__ outh) {
    constexpr int NT = FOUT / 16;
    constexpr int LD1 = (KB - F0) > 0 ? (KB - F0) : 1;
    int tid = threadIdx.x;
    int l = tid & 63;
    int w = tid >> 6;
    int row0 = blockIdx.x * 64 + w * 16;
    int r15 = l & 15;
    int kg = l >> 4;
    int rr = row0 + r15;
    if (rr > N_NODES - 1) rr = N_NODES - 1;  // clamp; stores are guarded

    f32x4 acc[NT];
#pragma unroll
    for (int ct = 0; ct < NT; ++ct) acc[ct] = (f32x4){0.f, 0.f, 0.f, 0.f};

    for (int k0 = 0; k0 < KB; k0 += 32) {
        int kl = k0 + kg * 8;
        const _Float16* ap;
        if (!DUAL || k0 < F0)
            ap = A0h + (size_t)rr * F0 + kl;
        else
            ap = A1h + (size_t)rr * LD1 + (kl - F0);
        half8v af = *(const half8v*)ap;
#pragma unroll
        for (int ct = 0; ct < NT; ++ct) {
            const _Float16* bp = Wt + (size_t)(ct * 16 + r15) * KB + kl;
            half8v bf = *(const half8v*)bp;
            acc[ct] = __builtin_amdgcn_mfma_f32_16x16x32_f16(af, bf, acc[ct], 0, 0, 0);
        }
    }

    int orow = row0 + kg * 4;
#pragma unroll
    for (int ct = 0; ct < NT; ++ct) {
        int col = ct * 16 + r15;
        float bv = RELU ? bias[col] : 0.f;
#pragma unroll
        for (int i = 0; i < 4; ++i) {
            int rw = orow + i;
            if (rw < N_NODES) {
                float v = acc[ct][i];
                if (RELU) v = fmaxf(v + bv, 0.f);
                out[(size_t)rw * FOUT + col] = v;
                if (WH) outh[(size_t)rw * FOUT + col] = f2h(v);
            }
        }
    }
}

// ---------------- pooling + linear + log_softmax ----------------

__global__ void pool_head_kernel(const float* __restrict__ h, const int* __restrict__ batch,
                                 const float* __restrict__ lw, const float* __restrict__ lb,
                                 float* __restrict__ out) {
    int g = blockIdx.x;
    int f = threadIdx.x;
    int s, e;
    {
        int lo = 0, hi = N_NODES;
        while (lo < hi) { int mid = (lo + hi) >> 1; if (batch[mid] < g) lo = mid + 1; else hi = mid; }
        s = lo;
        hi = N_NODES;
        while (lo < hi) { int mid = (lo + hi) >> 1; if (batch[mid] < g + 1) lo = mid + 1; else hi = mid; }
        e = lo;
    }
    float sum = 0.0f;
    for (int i = s; i < e; ++i) sum += h[(size_t)i * 128 + f];
    float cnt = (float)(e - s);
    float pooled = sum / fmaxf(cnt, 1.0f);

    __shared__ float l0[128], l1[128];
    l0[f] = pooled * lw[f * 2 + 0];
    l1[f] = pooled * lw[f * 2 + 1];
    __syncthreads();
    for (int sdt = 64; sdt > 0; sdt >>= 1) {
        if (f < sdt) { l0[f] += l0[f + sdt]; l1[f] += l1[f + sdt]; }
        __syncthreads();
    }
    if (f == 0) {
        float a = l0[0] + lb[0], b = l1[0] + lb[1];
        float m = fmaxf(a, b);
        float lse = m + logf(expf(a - m) + expf(b - m));
        out[g * 2 + 0] = a - lse;
        out[g * 2 + 1] = b - lse;
    }
}

// ---------------- forward-recurrence layer (layers 2-5) ----------------

template <int F, int FOUT, bool WH_OUT>
static void run_layer_fwd(const float* h, const _Float16* hh, float* Z, _Float16* Zh,
                          float* hout, _Float16* houth, const _Float16* Wt,
                          const float* b, const int* rp, const int2* ew, hipStream_t s) {
    constexpr int TPN = F / 4;
    int sp_grid = cdiv(N_NODES * TPN, 256);
    int mm_grid = cdiv(N_NODES, 64);
    const float* np_ = nullptr;
    // Z1 = L h
    spmm_fused<F, false, false, false, true><<<sp_grid, 256, 0, s>>>(
        rp, ew, hh, F, 1.f, np_, 0, 0.f, np_, 0, 0.f, np_, Z + 0 * F, 4 * F, Zh + 0 * F);
    // Z2 = 2 L Z1 - h
    spmm_fused<F, true, false, false, true><<<sp_grid, 256, 0, s>>>(
        rp, ew, Zh + 0 * F, 4 * F, 2.f, h, F, -1.f, np_, 0, 0.f, np_, Z + 1 * F, 4 * F, Zh + 1 * F);
    // Z3 = 2 L Z2 - Z1
    spmm_fused<F, true, false, false, true><<<sp_grid, 256, 0, s>>>(
        rp, ew, Zh + 1 * F, 4 * F, 2.f, Z + 0 * F, 4 * F, -1.f, np_, 0, 0.f, np_, Z + 2 * F, 4 * F, Zh + 2 * F);
    // Z4 = 2 L Z3 - Z2
    spmm_fused<F, true, false, false, true><<<sp_grid, 256, 0, s>>>(
        rp, ew, Zh + 2 * F, 4 * F, 2.f, Z + 1 * F, 4 * F, -1.f, np_, 0, 0.f, np_, Z + 3 * F, 4 * F, Zh + 3 * F);
    // out = [hh|Zh] @ W + b, relu (fp16 MFMA, fp32 accum)
    _Float16* nh_ = nullptr;
    mm_mfma<5 * F, F, FOUT, true, true, WH_OUT><<<mm_grid, 256, 0, s>>>(
        hh, Zh, Wt, b, hout, WH_OUT ? houth : nh_);
}

extern "C" void kernel_launch(void* const* d_in, const int* in_sizes, int n_in,
                              void* d_out, int out_size, void* d_ws, size_t ws_size,
                              hipStream_t stream) {
    const float* x = (const float*)d_in[0];
    const int* ei = (const int*)d_in[1];
    const int* batch = (const int*)d_in[2];
    const float* W1 = (const float*)d_in[3];
    const float* b1 = (const float*)d_in[4];
    const float* W2 = (const float*)d_in[5];
    const float* b2 = (const float*)d_in[6];
    const float* W3 = (const float*)d_in[7];
    const float* b3 = (const float*)d_in[8];
    const float* W4 = (const float*)d_in[9];
    const float* b4 = (const float*)d_in[10];
    const float* W5 = (const float*)d_in[11];
    const float* b5 = (const float*)d_in[12];
    const float* lin_w = (const float*)d_in[13];
    const float* lin_b = (const float*)d_in[14];
    const int* row = ei;
    const int* col = ei + N_EDGES;
    float* out = (float*)d_out;

    char* p = (char*)d_ws;
    auto alloc = [&](size_t bytes) {
        char* r = p;
        p += (bytes + 255) & ~(size_t)255;
        return r;
    };
    int* cnt = (int*)alloc((size_t)N_NODES * 4);
    int* rp = (int*)alloc((size_t)(N_NODES + 1) * 4);
    int* cursor = (int*)alloc((size_t)N_NODES * 4);
    int* bsum = (int*)alloc(256 * 4);
    float* dinv = (float*)alloc((size_t)N_NODES * 4);
    int2* ew = (int2*)alloc((size_t)N_EDGES * 8);
    float* big = (float*)alloc((size_t)N_NODES * 256 * 4);  // U [N,160] then Z [N,256]
    float* hA = (float*)alloc((size_t)N_NODES * 128 * 4);
    float* hB = (float*)alloc((size_t)N_NODES * 128 * 4);
    _Float16* Zh = (_Float16*)alloc((size_t)N_NODES * 256 * 2);  // Uh [N,160] then Zh [N,256]
    _Float16* hAh = (_Float16*)alloc((size_t)N_NODES * 128 * 2);  // xh, h1h/h3h
    _Float16* hBh = (_Float16*)alloc((size_t)N_NODES * 128 * 2);  // B*h, h2h/h4h
    _Float16* wt1 = (_Float16*)alloc((size_t)160 * 128 * 2);
    _Float16* wt2 = (_Float16*)alloc((size_t)32 * 160 * 2);
    _Float16* wt3 = (_Float16*)alloc((size_t)64 * 160 * 2);
    _Float16* wt4 = (_Float16*)alloc((size_t)64 * 320 * 2);
    _Float16* wt5 = (_Float16*)alloc((size_t)128 * 320 * 2);

    const int NB = cdiv(N_NODES, 256);  // 196
    hipMemsetAsync(cnt, 0, (size_t)N_NODES * 4, stream);
    count_kernel<<<cdiv(N_EDGES, 256), 256, 0, stream>>>(row, cnt, N_EDGES);
    block_scan_kernel<<<NB, 256, 0, stream>>>(cnt, rp, bsum, N_NODES);
    scan_bsum_kernel<<<1, 256, 0, stream>>>(bsum, NB);
    add_off_kernel<<<NB, 256, 0, stream>>>(rp, bsum, N_NODES);
    dinv_cursor_kernel<<<cdiv(N_NODES, 256), 256, 0, stream>>>(cnt, rp, dinv, cursor, N_NODES);
    fill_kernel<<<cdiv(N_EDGES, 256), 256, 0, stream>>>(row, col, dinv, cursor, ew, N_EDGES);

    // fp16 prep
    conv_x_kernel<<<cdiv(N_NODES * 128, 256), 256, 0, stream>>>(x, hAh);
    conv_wt1_kernel<<<cdiv(160 * 128, 256), 256, 0, stream>>>(W1, wt1);
    conv_wt_kernel<32, 160><<<cdiv(32 * 160, 256), 256, 0, stream>>>(W2, wt2);
    conv_wt_kernel<64, 160><<<cdiv(64 * 160, 256), 256, 0, stream>>>(W3, wt3);
    conv_wt_kernel<64, 320><<<cdiv(64 * 320, 256), 256, 0, stream>>>(W4, wt4);
    conv_wt_kernel<128, 320><<<cdiv(128 * 320, 256), 256, 0, stream>>>(W5, wt5);

    // ---- Layer 1 via Clenshaw in 32-dim space ----
    // U[n, k*32+fo] = (x @ W1[k])[n,fo]; fp16 co-out Uh for the gathers
    float* U = big;
    _Float16* Uh = Zh;  // [N,160], dead before layer-2 Zh use
    mm_mfma<128, 128, 160, false, false, true><<<cdiv(N_NODES, 64), 256, 0, stream>>>(
        hAh, (const _Float16*)nullptr, wt1, nullptr, U, Uh);
    float* B3 = hB;
    float* B2 = hB + (size_t)N_NODES * 32;
    float* B1 = hB + (size_t)N_NODES * 64;
    _Float16* B3h = hBh;
    _Float16* B2h = hBh + (size_t)N_NODES * 32;
    _Float16* B1h = hBh + (size_t)N_NODES * 64;
    float* h1 = hA;           // [N,32]
    _Float16* h1h = hAh;      // [N,32] (xh dead after layer-1 mm)
    const float* np_ = nullptr;
    int g32 = cdiv(N_NODES * 8, 256);
    // B3 = 2 L U4 + U3
    spmm_fused<32, true, false, false, true><<<g32, 256, 0, stream>>>(
        rp, ew, Uh + 128, 160, 2.f, U + 96, 160, 1.f, np_, 0, 0.f, np_, B3, 32, B3h);
    // B2 = 2 L B3 + U2 - U4
    spmm_fused<32, true, true, false, true><<<g32, 256, 0, stream>>>(
        rp, ew, B3h, 32, 2.f, U + 64, 160, 1.f, U + 128, 160, -1.f, np_, B2, 32, B2h);
    // B1 = 2 L B2 + U1 - B3
    spmm_fused<32, true, true, false, true><<<g32, 256, 0, stream>>>(
        rp, ew, B2h, 32, 2.f, U + 32, 160, 1.f, B3, 32, -1.f, np_, B1, 32, B1h);
    // h1 = relu( L B1 + U0 - B2 + b1 )
    spmm_fused<32, true, true, true, true><<<g32, 256, 0, stream>>>(
        rp, ew, B1h, 32, 1.f, U + 0, 160, 1.f, B2, 32, -1.f, b1, h1, 32, h1h);

    // ---- Layers 2-5: fp32 recurrence (fp16 gathers) + fp16 MFMA matmul ----
    float* Z = big;
    // L2: h1(hA,hAh) -> h2(hB,hBh)
    run_layer_fwd<32, 32, true>(h1, h1h, Z, Zh, hB, hBh, wt2, b2, rp, ew, stream);
    // L3: h2 -> h3(hA,hAh)
    run_layer_fwd<32, 64, true>(hB, hBh, Z, Zh, hA, hAh, wt3, b3, rp, ew, stream);
    // L4: h3 -> h4(hB,hBh)
    run_layer_fwd<64, 64, true>(hA, hAh, Z, Zh, hB, hBh, wt4, b4, rp, ew, stream);
    // L5: h4 -> h5(hA), no fp16 out
    run_layer_fwd<64, 128, false>(hB, hBh, Z, Zh, hA, (_Float16*)nullptr, wt5, b5, rp, ew, stream);

    pool_head_kernel<<<N_GRAPHS, 128, 0, stream>>>(hA, batch, lin_w, lin_b, out);
}

// Round 11
// 682.321 us; speedup vs baseline: 3.4006x; 1.0912x over previous
//
#include <hip/hip_runtime.h>

#define N_NODES 50000
#define N_GRAPHS 500
#define N_EDGES 800000

static inline int cdiv(int a, int b) { return (a + b - 1) / b; }

typedef _Float16 half8v __attribute__((ext_vector_type(8)));
typedef _Float16 half4v __attribute__((ext_vector_type(4)));
typedef __attribute__((ext_vector_type(4))) float f32x4;

__device__ __forceinline__ _Float16 f2h(float f) { return (_Float16)f; }

// ---------------- CSR build ----------------

__global__ void count_kernel(const int* __restrict__ row, int* __restrict__ cnt, int e) {
    int t = blockIdx.x * blockDim.x + threadIdx.x;
    if (t < e) atomicAdd(&cnt[row[t]], 1);
}

// 3-kernel scan: per-block exclusive scan + block sums, scan sums, add offsets.
__global__ void block_scan_kernel(const int* __restrict__ cnt, int* __restrict__ rp,
                                  int* __restrict__ bsum, int n) {
    __shared__ int buf[2][256];
    int t = threadIdx.x;
    int idx = blockIdx.x * 256 + t;
    int v = (idx < n) ? cnt[idx] : 0;
    buf[0][t] = v;
    __syncthreads();
    int s = 0;
#pragma unroll
    for (int off = 1; off < 256; off <<= 1) {
        int x = buf[s][t];
        if (t >= off) x += buf[s][t - off];
        buf[s ^ 1][t] = x;
        s ^= 1;
        __syncthreads();
    }
    if (idx < n) rp[idx] = buf[s][t] - v;  // exclusive within block
    if (t == 255) bsum[blockIdx.x] = buf[s][255];
}

__global__ void scan_bsum_kernel(int* __restrict__ bsum, int nb) {
    __shared__ int buf[2][256];
    int t = threadIdx.x;
    int v = (t < nb) ? bsum[t] : 0;
    buf[0][t] = v;
    __syncthreads();
    int s = 0;
#pragma unroll
    for (int off = 1; off < 256; off <<= 1) {
        int x = buf[s][t];
        if (t >= off) x += buf[s][t - off];
        buf[s ^ 1][t] = x;
        s ^= 1;
        __syncthreads();
    }
    if (t < nb) bsum[t] = buf[s][t] - v;  // exclusive
}

__global__ void add_off_kernel(int* __restrict__ rp, const int* __restrict__ bsum, int n) {
    int idx = blockIdx.x * 256 + threadIdx.x;
    if (idx < n) rp[idx] += bsum[idx >> 8];
    if (idx == 0) rp[n] = N_EDGES;
}

__global__ void dinv_cursor_kernel(const int* __restrict__ cnt, const int* __restrict__ rp,
                                   float* __restrict__ dinv, int* __restrict__ cursor, int n) {
    int t = blockIdx.x * blockDim.x + threadIdx.x;
    if (t < n) {
        int c = cnt[t];
        dinv[t] = (c > 0) ? rsqrtf((float)c) : 0.0f;
        cursor[t] = rp[t];
    }
}

// Packed 4B edge record: col (16 bits, N<2^16) | fp16 weight bits.
__global__ void fill_kernel(const int* __restrict__ row, const int* __restrict__ col,
                            const float* __restrict__ dinv, int* __restrict__ cursor,
                            unsigned* __restrict__ ew, int e) {
    int t = blockIdx.x * blockDim.x + threadIdx.x;
    if (t < e) {
        int r = row[t], c = col[t];
        int slot = atomicAdd(&cursor[r], 1);
        float w = -dinv[r] * dinv[c];
        unsigned short wb = __builtin_bit_cast(unsigned short, (_Float16)w);
        ew[slot] = ((unsigned)c << 16) | (unsigned)wb;
    }
}

// ---------------- fp16 conversions ----------------

// x [N,116] f32 -> xh [N,128] fp16 zero-padded
__global__ void conv_x_kernel(const float* __restrict__ x, _Float16* __restrict__ xh) {
    int t = blockIdx.x * blockDim.x + threadIdx.x;
    if (t >= N_NODES * 128) return;
    int r = t >> 7, c = t & 127;
    xh[t] = (c < 116) ? f2h(x[(size_t)r * 116 + c]) : (_Float16)0.f;
}

// W1 [5][116][32] -> wt1 [160][128] fp16, wt1[c][k] = k<116 ? W1[c/32][k][c%32] : 0
__global__ void conv_wt1_kernel(const float* __restrict__ W, _Float16* __restrict__ wt) {
    int t = blockIdx.x * blockDim.x + threadIdx.x;
    if (t >= 160 * 128) return;
    int c = t >> 7, k = t & 127;
    wt[t] = (k < 116) ? f2h(W[(c >> 5) * (116 * 32) + k * 32 + (c & 31)]) : (_Float16)0.f;
}

// W [KB, FOUT] f32 -> wt [FOUT][KB] fp16 transposed
template <int FOUT, int KB>
__global__ void conv_wt_kernel(const float* __restrict__ W, _Float16* __restrict__ wt) {
    int t = blockIdx.x * blockDim.x + threadIdx.x;
    if (t >= FOUT * KB) return;
    int c = t / KB, k = t % KB;
    wt[t] = f2h(W[(size_t)k * FOUT + c]);
}

// ---------------- fused SpMM (all-fp16): outh = fp16( alpha*L(src) + cA*A + cB*B (+bias,relu) )
// fp32 arithmetic internally; all tensor operands fp16.

template <int F, bool HAS_A, bool HAS_B, bool RELU>
__global__ __launch_bounds__(256) void spmm_fused(
    const int* __restrict__ rp, const unsigned* __restrict__ ew,
    const _Float16* __restrict__ src, int ld_s, float alpha,
    const _Float16* __restrict__ A, int ldA, float cA,
    const _Float16* __restrict__ B, int ldB, float cB,
    const float* __restrict__ bias, _Float16* __restrict__ outh, int ldO) {
    constexpr int TPN = F / 4;
    int t = blockIdx.x * blockDim.x + threadIdx.x;
    if (t >= N_NODES * TPN) return;
    int node = t / TPN;
    int f = (t % TPN) * 4;
    const _Float16* sf = src + f;
    int e0 = rp[node], e1 = rp[node + 1];
    float ax = 0.f, ay = 0.f, az = 0.f, aw = 0.f;
    int j = e0;
    for (; j + 3 < e1; j += 4) {
        unsigned ea = ew[j], eb = ew[j + 1], ec = ew[j + 2], ed = ew[j + 3];
        float w0 = (float)__builtin_bit_cast(_Float16, (unsigned short)ea);
        float w1 = (float)__builtin_bit_cast(_Float16, (unsigned short)eb);
        float w2 = (float)__builtin_bit_cast(_Float16, (unsigned short)ec);
        float w3 = (float)__builtin_bit_cast(_Float16, (unsigned short)ed);
        half4v v0 = *(const half4v*)(sf + (size_t)(ea >> 16) * ld_s);
        half4v v1 = *(const half4v*)(sf + (size_t)(eb >> 16) * ld_s);
        half4v v2 = *(const half4v*)(sf + (size_t)(ec >> 16) * ld_s);
        half4v v3 = *(const half4v*)(sf + (size_t)(ed >> 16) * ld_s);
        ax += w0 * (float)v0.x + w1 * (float)v1.x + w2 * (float)v2.x + w3 * (float)v3.x;
        ay += w0 * (float)v0.y + w1 * (float)v1.y + w2 * (float)v2.y + w3 * (float)v3.y;
        az += w0 * (float)v0.z + w1 * (float)v1.z + w2 * (float)v2.z + w3 * (float)v3.z;
        aw += w0 * (float)v0.w + w1 * (float)v1.w + w2 * (float)v2.w + w3 * (float)v3.w;
    }
    for (; j < e1; ++j) {
        unsigned ea = ew[j];
        float w0 = (float)__builtin_bit_cast(_Float16, (unsigned short)ea);
        half4v v0 = *(const half4v*)(sf + (size_t)(ea >> 16) * ld_s);
        ax += w0 * (float)v0.x;
        ay += w0 * (float)v0.y;
        az += w0 * (float)v0.z;
        aw += w0 * (float)v0.w;
    }
    float rx = alpha * ax, ry = alpha * ay, rz = alpha * az, rw = alpha * aw;
    if (HAS_A) {
        half4v a4 = *(const half4v*)(A + (size_t)node * ldA + f);
        rx += cA * (float)a4.x; ry += cA * (float)a4.y;
        rz += cA * (float)a4.z; rw += cA * (float)a4.w;
    }
    if (HAS_B) {
        half4v b4 = *(const half4v*)(B + (size_t)node * ldB + f);
        rx += cB * (float)b4.x; ry += cB * (float)b4.y;
        rz += cB * (float)b4.z; rw += cB * (float)b4.w;
    }
    if (RELU) {
        float4 bb = *(const float4*)(bias + f);
        rx = fmaxf(rx + bb.x, 0.f); ry = fmaxf(ry + bb.y, 0.f);
        rz = fmaxf(rz + bb.z, 0.f); rw = fmaxf(rw + bb.w, 0.f);
    }
    half4v h4;
    h4.x = f2h(rx); h4.y = f2h(ry); h4.z = f2h(rz); h4.w = f2h(rw);
    *(half4v*)(outh + (size_t)node * ldO + f) = h4;
}

// ---------------- MFMA matmul (fp16): outh[N,FOUT] = fp16([A0h|A1h][N,KB] @ Wt^T (+bias,relu))
// LDS-free; k-loop fully unrolled so the compiler can hoist all loads (MLP).
// C/D: col = lane&15, row = (lane>>4)*4 + reg  [verified layout].

template <int KB, int F0, int FOUT, bool DUAL, bool RELU>
__global__ __launch_bounds__(256) void mm_mfma(const _Float16* __restrict__ A0h,
                                               const _Float16* __restrict__ A1h,
                                               const _Float16* __restrict__ Wt,
                                               const float* __restrict__ bias,
                                               _Float16* __restrict__ outh) {
    constexpr int NT = FOUT / 16;
    constexpr int LD1 = (KB - F0) > 0 ? (KB - F0) : 1;
    int tid = threadIdx.x;
    int l = tid & 63;
    int w = tid >> 6;
    int row0 = blockIdx.x * 64 + w * 16;
    int r15 = l & 15;
    int kg = l >> 4;
    int rr = row0 + r15;
    if (rr > N_NODES - 1) rr = N_NODES - 1;  // clamp; stores are guarded

    f32x4 acc[NT];
#pragma unroll
    for (int ct = 0; ct < NT; ++ct) acc[ct] = (f32x4){0.f, 0.f, 0.f, 0.f};

#pragma unroll
    for (int k0 = 0; k0 < KB; k0 += 32) {
        int kl = k0 + kg * 8;
        const _Float16* ap;
        if (!DUAL || k0 < F0)
            ap = A0h + (size_t)rr * F0 + kl;
        else
            ap = A1h + (size_t)rr * LD1 + (kl - F0);
        half8v af = *(const half8v*)ap;
#pragma unroll
        for (int ct = 0; ct < NT; ++ct) {
            const _Float16* bp = Wt + (size_t)(ct * 16 + r15) * KB + kl;
            half8v bf = *(const half8v*)bp;
            acc[ct] = __builtin_amdgcn_mfma_f32_16x16x32_f16(af, bf, acc[ct], 0, 0, 0);
        }
    }

    int orow = row0 + kg * 4;
#pragma unroll
    for (int ct = 0; ct < NT; ++ct) {
        int col = ct * 16 + r15;
        float bv = RELU ? bias[col] : 0.f;
#pragma unroll
        for (int i = 0; i < 4; ++i) {
            int rw = orow + i;
            if (rw < N_NODES) {
                float v = acc[ct][i];
                if (RELU) v = fmaxf(v + bv, 0.f);
                outh[(size_t)rw * FOUT + col] = f2h(v);
            }
        }
    }
}

// ---------------- pooling + linear + log_softmax (fp16 input, fp32 math) ----------------

__global__ void pool_head_kernel(const _Float16* __restrict__ h, const int* __restrict__ batch,
                                 const float* __restrict__ lw, const float* __restrict__ lb,
                                 float* __restrict__ out) {
    int g = blockIdx.x;
    int f = threadIdx.x;
    int s, e;
    {
        int lo = 0, hi = N_NODES;
        while (lo < hi) { int mid = (lo + hi) >> 1; if (batch[mid] < g) lo = mid + 1; else hi = mid; }
        s = lo;
        hi = N_NODES;
        while (lo < hi) { int mid = (lo + hi) >> 1; if (batch[mid] < g + 1) lo = mid + 1; else hi = mid; }
        e = lo;
    }
    float sum = 0.0f;
    for (int i = s; i < e; ++i) sum += (float)h[(size_t)i * 128 + f];
    float cnt = (float)(e - s);
    float pooled = sum / fmaxf(cnt, 1.0f);

    __shared__ float l0[128], l1[128];
    l0[f] = pooled * lw[f * 2 + 0];
    l1[f] = pooled * lw[f * 2 + 1];
    __syncthreads();
    for (int sdt = 64; sdt > 0; sdt >>= 1) {
        if (f < sdt) { l0[f] += l0[f + sdt]; l1[f] += l1[f + sdt]; }
        __syncthreads();
    }
    if (f == 0) {
        float a = l0[0] + lb[0], b = l1[0] + lb[1];
        float m = fmaxf(a, b);
        float lse = m + logf(expf(a - m) + expf(b - m));
        out[g * 2 + 0] = a - lse;
        out[g * 2 + 1] = b - lse;
    }
}

// ---------------- forward-recurrence layer (layers 2-5), all-fp16 ----------------

template <int F, int FOUT>
static void run_layer_fwd(const _Float16* hh, _Float16* Zh, _Float16* houth,
                          const _Float16* Wt, const float* b, const int* rp,
                          const unsigned* ew, hipStream_t s) {
    constexpr int TPN = F / 4;
    int sp_grid = cdiv(N_NODES * TPN, 256);
    int mm_grid = cdiv(N_NODES, 64);
    const _Float16* nh_ = nullptr;
    // Z1 = L h
    spmm_fused<F, false, false, false><<<sp_grid, 256, 0, s>>>(
        rp, ew, hh, F, 1.f, nh_, 0, 0.f, nh_, 0, 0.f, nullptr, Zh + 0 * F, 4 * F);
    // Z2 = 2 L Z1 - h
    spmm_fused<F, true, false, false><<<sp_grid, 256, 0, s>>>(
        rp, ew, Zh + 0 * F, 4 * F, 2.f, hh, F, -1.f, nh_, 0, 0.f, nullptr, Zh + 1 * F, 4 * F);
    // Z3 = 2 L Z2 - Z1
    spmm_fused<F, true, false, false><<<sp_grid, 256, 0, s>>>(
        rp, ew, Zh + 1 * F, 4 * F, 2.f, Zh + 0 * F, 4 * F, -1.f, nh_, 0, 0.f, nullptr, Zh + 2 * F, 4 * F);
    // Z4 = 2 L Z3 - Z2
    spmm_fused<F, true, false, false><<<sp_grid, 256, 0, s>>>(
        rp, ew, Zh + 2 * F, 4 * F, 2.f, Zh + 1 * F, 4 * F, -1.f, nh_, 0, 0.f, nullptr, Zh + 3 * F, 4 * F);
    // out = relu([hh|Zh] @ W + b) in fp16
    mm_mfma<5 * F, F, FOUT, true, true><<<mm_grid, 256, 0, s>>>(hh, Zh, Wt, b, houth);
}

extern "C" void kernel_launch(void* const* d_in, const int* in_sizes, int n_in,
                              void* d_out, int out_size, void* d_ws, size_t ws_size,
                              hipStream_t stream) {
    const float* x = (const float*)d_in[0];
    const int* ei = (const int*)d_in[1];
    const int* batch = (const int*)d_in[2];
    const float* W1 = (const float*)d_in[3];
    const float* b1 = (const float*)d_in[4];
    const float* W2 = (const float*)d_in[5];
    const float* b2 = (const float*)d_in[6];
    const float* W3 = (const float*)d_in[7];
    const float* b3 = (const float*)d_in[8];
    const float* W4 = (const float*)d_in[9];
    const float* b4 = (const float*)d_in[10];
    const float* W5 = (const float*)d_in[11];
    const float* b5 = (const float*)d_in[12];
    const float* lin_w = (const float*)d_in[13];
    const float* lin_b = (const float*)d_in[14];
    const int* row = ei;
    const int* col = ei + N_EDGES;
    float* out = (float*)d_out;

    char* p = (char*)d_ws;
    auto alloc = [&](size_t bytes) {
        char* r = p;
        p += (bytes + 255) & ~(size_t)255;
        return r;
    };
    int* cnt = (int*)alloc((size_t)N_NODES * 4);
    int* rp = (int*)alloc((size_t)(N_NODES + 1) * 4);
    int* cursor = (int*)alloc((size_t)N_NODES * 4);
    int* bsum = (int*)alloc(256 * 4);
    float* dinv = (float*)alloc((size_t)N_NODES * 4);
    unsigned* ew = (unsigned*)alloc((size_t)N_EDGES * 4);
    _Float16* Zh = (_Float16*)alloc((size_t)N_NODES * 256 * 2);   // Uh [N,160] then Zh [N,256]
    _Float16* hAh = (_Float16*)alloc((size_t)N_NODES * 128 * 2);  // xh, h1h/h3h/h5h
    _Float16* hBh = (_Float16*)alloc((size_t)N_NODES * 128 * 2);  // B*h, h2h/h4h
    _Float16* wt1 = (_Float16*)alloc((size_t)160 * 128 * 2);
    _Float16* wt2 = (_Float16*)alloc((size_t)32 * 160 * 2);
    _Float16* wt3 = (_Float16*)alloc((size_t)64 * 160 * 2);
    _Float16* wt4 = (_Float16*)alloc((size_t)64 * 320 * 2);
    _Float16* wt5 = (_Float16*)alloc((size_t)128 * 320 * 2);

    const int NB = cdiv(N_NODES, 256);  // 196
    hipMemsetAsync(cnt, 0, (size_t)N_NODES * 4, stream);
    count_kernel<<<cdiv(N_EDGES, 256), 256, 0, stream>>>(row, cnt, N_EDGES);
    block_scan_kernel<<<NB, 256, 0, stream>>>(cnt, rp, bsum, N_NODES);
    scan_bsum_kernel<<<1, 256, 0, stream>>>(bsum, NB);
    add_off_kernel<<<NB, 256, 0, stream>>>(rp, bsum, N_NODES);
    dinv_cursor_kernel<<<cdiv(N_NODES, 256), 256, 0, stream>>>(cnt, rp, dinv, cursor, N_NODES);
    fill_kernel<<<cdiv(N_EDGES, 256), 256, 0, stream>>>(row, col, dinv, cursor, ew, N_EDGES);

    // fp16 prep
    conv_x_kernel<<<cdiv(N_NODES * 128, 256), 256, 0, stream>>>(x, hAh);
    conv_wt1_kernel<<<cdiv(160 * 128, 256), 256, 0, stream>>>(W1, wt1);
    conv_wt_kernel<32, 160><<<cdiv(32 * 160, 256), 256, 0, stream>>>(W2, wt2);
    conv_wt_kernel<64, 160><<<cdiv(64 * 160, 256), 256, 0, stream>>>(W3, wt3);
    conv_wt_kernel<64, 320><<<cdiv(64 * 320, 256), 256, 0, stream>>>(W4, wt4);
    conv_wt_kernel<128, 320><<<cdiv(128 * 320, 256), 256, 0, stream>>>(W5, wt5);

    // ---- Layer 1 via Clenshaw in 32-dim space (all-fp16) ----
    // Uh[n, k*32+fo] = fp16((x @ W1[k])[n,fo])
    _Float16* Uh = Zh;  // [N,160]; dead before layer-2 Zh use
    const _Float16* nh_ = nullptr;
    mm_mfma<128, 128, 160, false, false><<<cdiv(N_NODES, 64), 256, 0, stream>>>(
        hAh, nh_, wt1, nullptr, Uh);
    _Float16* B3h = hBh;
    _Float16* B2h = hBh + (size_t)N_NODES * 32;
    _Float16* B1h = hBh + (size_t)N_NODES * 64;
    _Float16* h1h = hAh;  // xh dead after layer-1 mm
    int g32 = cdiv(N_NODES * 8, 256);
    // B3 = 2 L U4 + U3
    spmm_fused<32, true, false, false><<<g32, 256, 0, stream>>>(
        rp, ew, Uh + 128, 160, 2.f, Uh + 96, 160, 1.f, nh_, 0, 0.f, nullptr, B3h, 32);
    // B2 = 2 L B3 + U2 - U4
    spmm_fused<32, true, true, false><<<g32, 256, 0, stream>>>(
        rp, ew, B3h, 32, 2.f, Uh + 64, 160, 1.f, Uh + 128, 160, -1.f, nullptr, B2h, 32);
    // B1 = 2 L B2 + U1 - B3
    spmm_fused<32, true, true, false><<<g32, 256, 0, stream>>>(
        rp, ew, B2h, 32, 2.f, Uh + 32, 160, 1.f, B3h, 32, -1.f, nullptr, B1h, 32);
    // h1 = relu( L B1 + U0 - B2 + b1 )
    spmm_fused<32, true, true, true><<<g32, 256, 0, stream>>>(
        rp, ew, B1h, 32, 1.f, Uh + 0, 160, 1.f, B2h, 32, -1.f, b1, h1h, 32);

    // ---- Layers 2-5: fp16 recurrence + fp16 MFMA matmul ----
    // L2: h1(hAh) -> h2(hBh)
    run_layer_fwd<32, 32>(h1h, Zh, hBh, wt2, b2, rp, ew, stream);
    // L3: h2 -> h3(hAh)
    run_layer_fwd<32, 64>(hBh, Zh, hAh, wt3, b3, rp, ew, stream);
    // L4: h3 -> h4(hBh)
    run_layer_fwd<64, 64>(hAh, Zh, hBh, wt4, b4, rp, ew, stream);
    // L5: h4 -> h5(hAh)
    run_layer_fwd<64, 128>(hBh, Zh, hAh, wt5, b5, rp, ew, stream);

    pool_head_kernel<<<N_GRAPHS, 128, 0, stream>>>(hAh, batch, lin_w, lin_b, out);
}

// Round 12
// 620.957 us; speedup vs baseline: 3.7366x; 1.0988x over previous
//
#include <hip/hip_runtime.h>

#define N_NODES 50000
#define N_GRAPHS 500
#define N_EDGES 800000

static inline int cdiv(int a, int b) { return (a + b - 1) / b; }

typedef _Float16 half8v __attribute__((ext_vector_type(8)));
typedef _Float16 half4v __attribute__((ext_vector_type(4)));
typedef __attribute__((ext_vector_type(4))) float f32x4;

__device__ __forceinline__ _Float16 f2h(float f) { return (_Float16)f; }

// ---------------- CSR build ----------------

__global__ void count_kernel(const int* __restrict__ row, int* __restrict__ cnt, int e) {
    int t = blockIdx.x * blockDim.x + threadIdx.x;
    if (t < e) atomicAdd(&cnt[row[t]], 1);
}

__global__ void block_scan_kernel(const int* __restrict__ cnt, int* __restrict__ rp,
                                  int* __restrict__ bsum, int n) {
    __shared__ int buf[2][256];
    int t = threadIdx.x;
    int idx = blockIdx.x * 256 + t;
    int v = (idx < n) ? cnt[idx] : 0;
    buf[0][t] = v;
    __syncthreads();
    int s = 0;
#pragma unroll
    for (int off = 1; off < 256; off <<= 1) {
        int x = buf[s][t];
        if (t >= off) x += buf[s][t - off];
        buf[s ^ 1][t] = x;
        s ^= 1;
        __syncthreads();
    }
    if (idx < n) rp[idx] = buf[s][t] - v;  // exclusive within block
    if (t == 255) bsum[blockIdx.x] = buf[s][255];
}

__global__ void scan_bsum_kernel(int* __restrict__ bsum, int nb) {
    __shared__ int buf[2][256];
    int t = threadIdx.x;
    int v = (t < nb) ? bsum[t] : 0;
    buf[0][t] = v;
    __syncthreads();
    int s = 0;
#pragma unroll
    for (int off = 1; off < 256; off <<= 1) {
        int x = buf[s][t];
        if (t >= off) x += buf[s][t - off];
        buf[s ^ 1][t] = x;
        s ^= 1;
        __syncthreads();
    }
    if (t < nb) bsum[t] = buf[s][t] - v;  // exclusive
}

__global__ void add_off_kernel(int* __restrict__ rp, const int* __restrict__ bsum, int n) {
    int idx = blockIdx.x * 256 + threadIdx.x;
    if (idx < n) rp[idx] += bsum[idx >> 8];
    if (idx == 0) rp[n] = N_EDGES;
}

__global__ void dinv_cursor_kernel(const int* __restrict__ cnt, const int* __restrict__ rp,
                                   float* __restrict__ dinv, int* __restrict__ cursor, int n) {
    int t = blockIdx.x * blockDim.x + threadIdx.x;
    if (t < n) {
        int c = cnt[t];
        dinv[t] = (c > 0) ? rsqrtf((float)c) : 0.0f;
        cursor[t] = rp[t];
    }
}

// Packed 4B edge record: col (16 bits, N<2^16) | fp16 weight bits.
__global__ void fill_kernel(const int* __restrict__ row, const int* __restrict__ col,
                            const float* __restrict__ dinv, int* __restrict__ cursor,
                            unsigned* __restrict__ ew, int e) {
    int t = blockIdx.x * blockDim.x + threadIdx.x;
    if (t < e) {
        int r = row[t], c = col[t];
        int slot = atomicAdd(&cursor[r], 1);
        float w = -dinv[r] * dinv[c];
        unsigned short wb = __builtin_bit_cast(unsigned short, (_Float16)w);
        ew[slot] = ((unsigned)c << 16) | (unsigned)wb;
    }
}

// ---------------- fp16 conversions ----------------

__global__ void conv_x_kernel(const float* __restrict__ x, _Float16* __restrict__ xh) {
    int t = blockIdx.x * blockDim.x + threadIdx.x;
    if (t >= N_NODES * 128) return;
    int r = t >> 7, c = t & 127;
    xh[t] = (c < 116) ? f2h(x[(size_t)r * 116 + c]) : (_Float16)0.f;
}

__global__ void conv_wt1_kernel(const float* __restrict__ W, _Float16* __restrict__ wt) {
    int t = blockIdx.x * blockDim.x + threadIdx.x;
    if (t >= 160 * 128) return;
    int c = t >> 7, k = t & 127;
    wt[t] = (k < 116) ? f2h(W[(c >> 5) * (116 * 32) + k * 32 + (c & 31)]) : (_Float16)0.f;
}

template <int FOUT, int KB>
__global__ void conv_wt_kernel(const float* __restrict__ W, _Float16* __restrict__ wt) {
    int t = blockIdx.x * blockDim.x + threadIdx.x;
    if (t >= FOUT * KB) return;
    int c = t / KB, k = t % KB;
    wt[t] = f2h(W[(size_t)k * FOUT + c]);
}

// ---------------- fused SpMM (all-fp16, 8-deep gather MLP) ----------------

template <int F, bool HAS_A, bool HAS_B, bool RELU>
__global__ __launch_bounds__(256) void spmm_fused(
    const int* __restrict__ rp, const unsigned* __restrict__ ew,
    const _Float16* __restrict__ src, int ld_s, float alpha,
    const _Float16* __restrict__ A, int ldA, float cA,
    const _Float16* __restrict__ B, int ldB, float cB,
    const float* __restrict__ bias, _Float16* __restrict__ outh, int ldO) {
    constexpr int TPN = F / 4;
    int t = blockIdx.x * blockDim.x + threadIdx.x;
    if (t >= N_NODES * TPN) return;
    int node = t / TPN;
    int f = (t % TPN) * 4;
    const _Float16* sf = src + f;
    int e0 = rp[node], e1 = rp[node + 1];
    float ax = 0.f, ay = 0.f, az = 0.f, aw = 0.f;
    int j = e0;
    for (; j + 7 < e1; j += 8) {
        unsigned e_[8];
#pragma unroll
        for (int u = 0; u < 8; ++u) e_[u] = ew[j + u];
        half4v v_[8];
#pragma unroll
        for (int u = 0; u < 8; ++u) v_[u] = *(const half4v*)(sf + (size_t)(e_[u] >> 16) * ld_s);
#pragma unroll
        for (int u = 0; u < 8; ++u) {
            float w = (float)__builtin_bit_cast(_Float16, (unsigned short)e_[u]);
            ax += w * (float)v_[u].x;
            ay += w * (float)v_[u].y;
            az += w * (float)v_[u].z;
            aw += w * (float)v_[u].w;
        }
    }
    for (; j + 3 < e1; j += 4) {
        unsigned e_[4];
#pragma unroll
        for (int u = 0; u < 4; ++u) e_[u] = ew[j + u];
        half4v v_[4];
#pragma unroll
        for (int u = 0; u < 4; ++u) v_[u] = *(const half4v*)(sf + (size_t)(e_[u] >> 16) * ld_s);
#pragma unroll
        for (int u = 0; u < 4; ++u) {
            float w = (float)__builtin_bit_cast(_Float16, (unsigned short)e_[u]);
            ax += w * (float)v_[u].x;
            ay += w * (float)v_[u].y;
            az += w * (float)v_[u].z;
            aw += w * (float)v_[u].w;
        }
    }
    for (; j < e1; ++j) {
        unsigned ea = ew[j];
        float w0 = (float)__builtin_bit_cast(_Float16, (unsigned short)ea);
        half4v v0 = *(const half4v*)(sf + (size_t)(ea >> 16) * ld_s);
        ax += w0 * (float)v0.x;
        ay += w0 * (float)v0.y;
        az += w0 * (float)v0.z;
        aw += w0 * (float)v0.w;
    }
    float rx = alpha * ax, ry = alpha * ay, rz = alpha * az, rw = alpha * aw;
    if (HAS_A) {
        half4v a4 = *(const half4v*)(A + (size_t)node * ldA + f);
        rx += cA * (float)a4.x; ry += cA * (float)a4.y;
        rz += cA * (float)a4.z; rw += cA * (float)a4.w;
    }
    if (HAS_B) {
        half4v b4 = *(const half4v*)(B + (size_t)node * ldB + f);
        rx += cB * (float)b4.x; ry += cB * (float)b4.y;
        rz += cB * (float)b4.z; rw += cB * (float)b4.w;
    }
    if (RELU) {
        float4 bb = *(const float4*)(bias + f);
        rx = fmaxf(rx + bb.x, 0.f); ry = fmaxf(ry + bb.y, 0.f);
        rz = fmaxf(rz + bb.z, 0.f); rw = fmaxf(rw + bb.w, 0.f);
    }
    half4v h4;
    h4.x = f2h(rx); h4.y = f2h(ry); h4.z = f2h(rz); h4.w = f2h(rw);
    *(half4v*)(outh + (size_t)node * ldO + f) = h4;
}

// ---------------- MFMA matmul (fp16, W staged in LDS) ----------------
// Block = 256 thr = 4 waves, BM = 64 rows (wave w: rows blk*64+w*16..+15).
// W chunk (KC k-cols x FOUT) staged in LDS with +8 fp16 row pad; B-frags are
// ds_read_b128 (~4-way bank alias, 1.58x — cheap) instead of 16-segment L2 loads.
// A-frags remain direct global loads (one 64B line per 4 lanes).
// C/D: col = lane&15, row = (lane>>4)*4 + reg  [verified layout].

template <int KB, int F0, int FOUT, bool DUAL, bool RELU>
__global__ __launch_bounds__(256) void mm_mfma(const _Float16* __restrict__ A0h,
                                               const _Float16* __restrict__ A1h,
                                               const _Float16* __restrict__ Wt,
                                               const float* __restrict__ bias,
                                               _Float16* __restrict__ outh) {
    constexpr int NT = FOUT / 16;
    constexpr int LD1 = (KB - F0) > 0 ? (KB - F0) : 1;
    constexpr int KC = (KB > 160) ? 160 : KB;  // k-chunk staged per pass
    constexpr int NCH = KB / KC;               // 1 or 2
    constexpr int LDW = KC + 8;                // fp16 units; keeps 16B row alignment
    __shared__ _Float16 lw[FOUT][LDW];

    int tid = threadIdx.x;
    int l = tid & 63;
    int w = tid >> 6;
    int row0 = blockIdx.x * 64 + w * 16;
    int r15 = l & 15;
    int kg = l >> 4;
    int rr = row0 + r15;
    if (rr > N_NODES - 1) rr = N_NODES - 1;  // clamp; stores are guarded

    f32x4 acc[NT];
#pragma unroll
    for (int ct = 0; ct < NT; ++ct) acc[ct] = (f32x4){0.f, 0.f, 0.f, 0.f};

#pragma unroll
    for (int ch = 0; ch < NCH; ++ch) {
        constexpr int C8 = KC / 8;
        int c0 = ch * KC;
        // stage W chunk: coalesced 16B global loads -> LDS
        for (int idx = tid; idx < FOUT * C8; idx += 256) {
            int r = idx / C8, c8 = idx - r * C8;
            *(half8v*)&lw[r][c8 * 8] = *(const half8v*)(Wt + (size_t)r * KB + c0 + c8 * 8);
        }
        __syncthreads();
#pragma unroll
        for (int k0 = 0; k0 < KC; k0 += 32) {
            int gc = c0 + k0;  // compile-time (both loops unrolled)
            int kl = gc + kg * 8;
            const _Float16* ap;
            if (!DUAL || gc < F0)
                ap = A0h + (size_t)rr * F0 + kl;
            else
                ap = A1h + (size_t)rr * LD1 + (kl - F0);
            half8v af = *(const half8v*)ap;
#pragma unroll
            for (int ct = 0; ct < NT; ++ct) {
                half8v bf = *(const half8v*)&lw[ct * 16 + r15][k0 + kg * 8];
                acc[ct] = __builtin_amdgcn_mfma_f32_16x16x32_f16(af, bf, acc[ct], 0, 0, 0);
            }
        }
        __syncthreads();
    }

    int orow = row0 + kg * 4;
#pragma unroll
    for (int ct = 0; ct < NT; ++ct) {
        int col = ct * 16 + r15;
        float bv = RELU ? bias[col] : 0.f;
#pragma unroll
        for (int i = 0; i < 4; ++i) {
            int rw = orow + i;
            if (rw < N_NODES) {
                float v = acc[ct][i];
                if (RELU) v = fmaxf(v + bv, 0.f);
                outh[(size_t)rw * FOUT + col] = f2h(v);
            }
        }
    }
}

// ---------------- pooling + linear + log_softmax (fp16 input, fp32 math) ----------------

__global__ void pool_head_kernel(const _Float16* __restrict__ h, const int* __restrict__ batch,
                                 const float* __restrict__ lw, const float* __restrict__ lb,
                                 float* __restrict__ out) {
    int g = blockIdx.x;
    int f = threadIdx.x;
    int s, e;
    {
        int lo = 0, hi = N_NODES;
        while (lo < hi) { int mid = (lo + hi) >> 1; if (batch[mid] < g) lo = mid + 1; else hi = mid; }
        s = lo;
        hi = N_NODES;
        while (lo < hi) { int mid = (lo + hi) >> 1; if (batch[mid] < g + 1) lo = mid + 1; else hi = mid; }
        e = lo;
    }
    float sum = 0.0f;
    for (int i = s; i < e; ++i) sum += (float)h[(size_t)i * 128 + f];
    float cnt = (float)(e - s);
    float pooled = sum / fmaxf(cnt, 1.0f);

    __shared__ float l0[128], l1[128];
    l0[f] = pooled * lw[f * 2 + 0];
    l1[f] = pooled * lw[f * 2 + 1];
    __syncthreads();
    for (int sdt = 64; sdt > 0; sdt >>= 1) {
        if (f < sdt) { l0[f] += l0[f + sdt]; l1[f] += l1[f + sdt]; }
        __syncthreads();
    }
    if (f == 0) {
        float a = l0[0] + lb[0], b = l1[0] + lb[1];
        float m = fmaxf(a, b);
        float lse = m + logf(expf(a - m) + expf(b - m));
        out[g * 2 + 0] = a - lse;
        out[g * 2 + 1] = b - lse;
    }
}

// ---------------- forward-recurrence layer (layers 2-5), all-fp16 ----------------

template <int F, int FOUT>
static void run_layer_fwd(const _Float16* hh, _Float16* Zh, _Float16* houth,
                          const _Float16* Wt, const float* b, const int* rp,
                          const unsigned* ew, hipStream_t s) {
    constexpr int TPN = F / 4;
    int sp_grid = cdiv(N_NODES * TPN, 256);
    int mm_grid = cdiv(N_NODES, 64);
    const _Float16* nh_ = nullptr;
    // Z1 = L h
    spmm_fused<F, false, false, false><<<sp_grid, 256, 0, s>>>(
        rp, ew, hh, F, 1.f, nh_, 0, 0.f, nh_, 0, 0.f, nullptr, Zh + 0 * F, 4 * F);
    // Z2 = 2 L Z1 - h
    spmm_fused<F, true, false, false><<<sp_grid, 256, 0, s>>>(
        rp, ew, Zh + 0 * F, 4 * F, 2.f, hh, F, -1.f, nh_, 0, 0.f, nullptr, Zh + 1 * F, 4 * F);
    // Z3 = 2 L Z2 - Z1
    spmm_fused<F, true, false, false><<<sp_grid, 256, 0, s>>>(
        rp, ew, Zh + 1 * F, 4 * F, 2.f, Zh + 0 * F, 4 * F, -1.f, nh_, 0, 0.f, nullptr, Zh + 2 * F, 4 * F);
    // Z4 = 2 L Z3 - Z2
    spmm_fused<F, true, false, false><<<sp_grid, 256, 0, s>>>(
        rp, ew, Zh + 2 * F, 4 * F, 2.f, Zh + 1 * F, 4 * F, -1.f, nh_, 0, 0.f, nullptr, Zh + 3 * F, 4 * F);
    // out = relu([hh|Zh] @ W + b) in fp16
    mm_mfma<5 * F, F, FOUT, true, true><<<mm_grid, 256, 0, s>>>(hh, Zh, Wt, b, houth);
}

extern "C" void kernel_launch(void* const* d_in, const int* in_sizes, int n_in,
                              void* d_out, int out_size, void* d_ws, size_t ws_size,
                              hipStream_t stream) {
    const float* x = (const float*)d_in[0];
    const int* ei = (const int*)d_in[1];
    const int* batch = (const int*)d_in[2];
    const float* W1 = (const float*)d_in[3];
    const float* b1 = (const float*)d_in[4];
    const float* W2 = (const float*)d_in[5];
    const float* b2 = (const float*)d_in[6];
    const float* W3 = (const float*)d_in[7];
    const float* b3 = (const float*)d_in[8];
    const float* W4 = (const float*)d_in[9];
    const float* b4 = (const float*)d_in[10];
    const float* W5 = (const float*)d_in[11];
    const float* b5 = (const float*)d_in[12];
    const float* lin_w = (const float*)d_in[13];
    const float* lin_b = (const float*)d_in[14];
    const int* row = ei;
    const int* col = ei + N_EDGES;
    float* out = (float*)d_out;

    char* p = (char*)d_ws;
    auto alloc = [&](size_t bytes) {
        char* r = p;
        p += (bytes + 255) & ~(size_t)255;
        return r;
    };
    int* cnt = (int*)alloc((size_t)N_NODES * 4);
    int* rp = (int*)alloc((size_t)(N_NODES + 1) * 4);
    int* cursor = (int*)alloc((size_t)N_NODES * 4);
    int* bsum = (int*)alloc(256 * 4);
    float* dinv = (float*)alloc((size_t)N_NODES * 4);
    unsigned* ew = (unsigned*)alloc((size_t)N_EDGES * 4);
    _Float16* Zh = (_Float16*)alloc((size_t)N_NODES * 256 * 2);   // Uh [N,160] then Zh [N,256]
    _Float16* hAh = (_Float16*)alloc((size_t)N_NODES * 128 * 2);  // xh, h1h/h3h/h5h
    _Float16* hBh = (_Float16*)alloc((size_t)N_NODES * 128 * 2);  // B*h, h2h/h4h
    _Float16* wt1 = (_Float16*)alloc((size_t)160 * 128 * 2);
    _Float16* wt2 = (_Float16*)alloc((size_t)32 * 160 * 2);
    _Float16* wt3 = (_Float16*)alloc((size_t)64 * 160 * 2);
    _Float16* wt4 = (_Float16*)alloc((size_t)64 * 320 * 2);
    _Float16* wt5 = (_Float16*)alloc((size_t)128 * 320 * 2);

    const int NB = cdiv(N_NODES, 256);  // 196
    hipMemsetAsync(cnt, 0, (size_t)N_NODES * 4, stream);
    count_kernel<<<cdiv(N_EDGES, 256), 256, 0, stream>>>(row, cnt, N_EDGES);
    block_scan_kernel<<<NB, 256, 0, stream>>>(cnt, rp, bsum, N_NODES);
    scan_bsum_kernel<<<1, 256, 0, stream>>>(bsum, NB);
    add_off_kernel<<<NB, 256, 0, stream>>>(rp, bsum, N_NODES);
    dinv_cursor_kernel<<<cdiv(N_NODES, 256), 256, 0, stream>>>(cnt, rp, dinv, cursor, N_NODES);
    fill_kernel<<<cdiv(N_EDGES, 256), 256, 0, stream>>>(row, col, dinv, cursor, ew, N_EDGES);

    // fp16 prep
    conv_x_kernel<<<cdiv(N_NODES * 128, 256), 256, 0, stream>>>(x, hAh);
    conv_wt1_kernel<<<cdiv(160 * 128, 256), 256, 0, stream>>>(W1, wt1);
    conv_wt_kernel<32, 160><<<cdiv(32 * 160, 256), 256, 0, stream>>>(W2, wt2);
    conv_wt_kernel<64, 160><<<cdiv(64 * 160, 256), 256, 0, stream>>>(W3, wt3);
    conv_wt_kernel<64, 320><<<cdiv(64 * 320, 256), 256, 0, stream>>>(W4, wt4);
    conv_wt_kernel<128, 320><<<cdiv(128 * 320, 256), 256, 0, stream>>>(W5, wt5);

    // ---- Layer 1 via Clenshaw in 32-dim space (all-fp16) ----
    _Float16* Uh = Zh;  // [N,160]; dead before layer-2 Zh use
    const _Float16* nh_ = nullptr;
    mm_mfma<128, 128, 160, false, false><<<cdiv(N_NODES, 64), 256, 0, stream>>>(
        hAh, nh_, wt1, nullptr, Uh);
    _Float16* B3h = hBh;
    _Float16* B2h = hBh + (size_t)N_NODES * 32;
    _Float16* B1h = hBh + (size_t)N_NODES * 64;
    _Float16* h1h = hAh;  // xh dead after layer-1 mm
    int g32 = cdiv(N_NODES * 8, 256);
    // B3 = 2 L U4 + U3
    spmm_fused<32, true, false, false><<<g32, 256, 0, stream>>>(
        rp, ew, Uh + 128, 160, 2.f, Uh + 96, 160, 1.f, nh_, 0, 0.f, nullptr, B3h, 32);
    // B2 = 2 L B3 + U2 - U4
    spmm_fused<32, true, true, false><<<g32, 256, 0, stream>>>(
        rp, ew, B3h, 32, 2.f, Uh + 64, 160, 1.f, Uh + 128, 160, -1.f, nullptr, B2h, 32);
    // B1 = 2 L B2 + U1 - B3
    spmm_fused<32, true, true, false><<<g32, 256, 0, stream>>>(
        rp, ew, B2h, 32, 2.f, Uh + 32, 160, 1.f, B3h, 32, -1.f, nullptr, B1h, 32);
    // h1 = relu( L B1 + U0 - B2 + b1 )
    spmm_fused<32, true, true, true><<<g32, 256, 0, stream>>>(
        rp, ew, B1h, 32, 1.f, Uh + 0, 160, 1.f, B2h, 32, -1.f, b1, h1h, 32);

    // ---- Layers 2-5: fp16 recurrence + fp16 MFMA matmul ----
    run_layer_fwd<32, 32>(h1h, Zh, hBh, wt2, b2, rp, ew, stream);
    run_layer_fwd<32, 64>(hBh, Zh, hAh, wt3, b3, rp, ew, stream);
    run_layer_fwd<64, 64>(hAh, Zh, hBh, wt4, b4, rp, ew, stream);
    run_layer_fwd<64, 128>(hBh, Zh, hAh, wt5, b5, rp, ew, stream);

    pool_head_kernel<<<N_GRAPHS, 128, 0, stream>>>(hAh, batch, lin_w, lin_b, out);
}